// Round 1
// baseline (2405.545 us; speedup 1.0000x reference)
//
#include <hip/hip_runtime.h>
#include <math.h>

#define BN_EPS 1e-5f

// ---------------------------------------------------------------------------
// Kernel A: conv1 (k=3, pad=1, 1->16 ch) + ReLU, and channel means (pooled).
// One block per sample. 256 threads: thread t -> channel c = t>>4,
// l in [(t&15)*32, +32).
// ---------------------------------------------------------------------------
__global__ __launch_bounds__(256) void conv1_kernel(
    const float* __restrict__ x, const float* __restrict__ w,
    const float* __restrict__ bias, float* __restrict__ h,
    float* __restrict__ pooled) {
  __shared__ float xs[514];
  __shared__ float psum[256];
  const int b = blockIdx.x;
  const int t = threadIdx.x;
  for (int i = t; i < 512; i += 256) xs[i + 1] = x[b * 512 + i];
  if (t == 0) { xs[0] = 0.f; xs[513] = 0.f; }
  __syncthreads();
  const int c  = t >> 4;
  const int l0 = (t & 15) * 32;
  const float w0 = w[c * 3 + 0], w1 = w[c * 3 + 1], w2 = w[c * 3 + 2];
  const float bb = bias[c];
  float s = 0.f;
  float* hrow = h + ((size_t)b * 16 + c) * 512;
  for (int j = 0; j < 32; ++j) {
    const int l = l0 + j;
    float v = fmaf(w0, xs[l], fmaf(w1, xs[l + 1], fmaf(w2, xs[l + 2], bb)));
    v = fmaxf(v, 0.f);
    hrow[l] = v;
    s += v;
  }
  psum[t] = s;
  __syncthreads();
  if ((t & 15) == 0) {
    float tot = 0.f;
    for (int k = 0; k < 16; ++k) tot += psum[t + k];
    pooled[b * 16 + c] = tot * (1.f / 512.f);
  }
}

// ---------------------------------------------------------------------------
// Kernel B: router. logits -> softmax -> top2 -> renormalized gates, plus the
// load-balance cv^2 scalar. One block of 64 threads (thread = sample).
// ---------------------------------------------------------------------------
__global__ void router_kernel(const float* __restrict__ pooled,
                              const float* __restrict__ rw,
                              const float* __restrict__ rb,
                              float* __restrict__ pair_g,
                              int* __restrict__ pair_e,
                              float* __restrict__ out_cv) {
  __shared__ float probs_l[64][8];
  __shared__ float mp[8];
  const int t = threadIdx.x;
  {
    float pl[16];
    for (int c = 0; c < 16; ++c) pl[c] = pooled[t * 16 + c];
    float lg[8];
    float mx = -1e30f;
    for (int e = 0; e < 8; ++e) {
      float a = rb[e];
      for (int c = 0; c < 16; ++c) a = fmaf(pl[c], rw[e * 16 + c], a);
      lg[e] = a;
      mx = fmaxf(mx, a);
    }
    float sum = 0.f;
    for (int e = 0; e < 8; ++e) { lg[e] = expf(lg[e] - mx); sum += lg[e]; }
    const float inv = 1.f / sum;
    for (int e = 0; e < 8; ++e) { lg[e] *= inv; probs_l[t][e] = lg[e]; }
    int e1 = 0; float p1 = lg[0];
    for (int e = 1; e < 8; ++e) if (lg[e] > p1) { p1 = lg[e]; e1 = e; }
    int e2 = -1; float p2 = -1.f;
    for (int e = 0; e < 8; ++e) if (e != e1 && lg[e] > p2) { p2 = lg[e]; e2 = e; }
    const float gs = 1.f / (p1 + p2);
    pair_e[2 * t]     = e1; pair_g[2 * t]     = p1 * gs;
    pair_e[2 * t + 1] = e2; pair_g[2 * t + 1] = p2 * gs;
  }
  __syncthreads();
  if (t < 8) {
    float s = 0.f;
    for (int b = 0; b < 64; ++b) s += probs_l[b][t];
    mp[t] = s * (1.f / 64.f);
  }
  __syncthreads();
  if (t == 0) {
    float mean = 0.f;
    for (int e = 0; e < 8; ++e) mean += mp[e];
    mean *= (1.f / 8.f);
    float var = 0.f;
    for (int e = 0; e < 8; ++e) { const float d = mp[e] - mean; var = fmaf(d, d, var); }
    var *= (1.f / 7.f);
    const float cv = sqrtf(var) / (mean + 1e-10f);
    *out_cv = cv * cv;
  }
}

// ---------------------------------------------------------------------------
// Kernel C: expert conv block (conv k -> BN -> ReLU -> maxpool2), sparse over
// the 128 (sample, slot) pairs. grid = (CO/(CONC*NCO), 128 pairs).
// Input [CI][LIN] staged to LDS in CSPLIT passes (zero-padded by PAD).
// Thread: pooled pos j = t % LOUT, co group cs = t / LOUT; NCO channels
// register-blocked (2*NCO accumulators), sliding-window input reuse.
// ---------------------------------------------------------------------------
template <int CI, int LIN, int K, int PAD, int CO, int CONC, int NCO,
          int CSPLIT, bool IN_IS_H>
__global__ __launch_bounds__(256) void conv_block(
    const float* __restrict__ in, const float* __restrict__ ew,
    const float* __restrict__ eb, const float* __restrict__ eg,
    const float* __restrict__ ebb, const float* __restrict__ em,
    const float* __restrict__ ev, const int* __restrict__ pair_e,
    float* __restrict__ out) {
  constexpr int LOUT = LIN / 2;
  constexpr int CIT  = CI / CSPLIT;
  constexpr int LPAD = LIN + 2 * PAD;
  __shared__ float xs[CIT * LPAD];

  const int p = blockIdx.y;
  const int t = threadIdx.x;
  const int e = pair_e[p];
  const float* inp = IN_IS_H ? (in + (size_t)(p >> 1) * CI * LIN)
                             : (in + (size_t)p * CI * LIN);
  const int j  = t % LOUT;
  const int cs = t / LOUT;
  const int co0 = blockIdx.x * (CONC * NCO) + cs * NCO;
  const float* wbase = ew + ((size_t)e * CO + co0) * (CI * K);

  float acc0[NCO], acc1[NCO];
#pragma unroll
  for (int n = 0; n < NCO; ++n) { acc0[n] = 0.f; acc1[n] = 0.f; }

  for (int ss = 0; ss < CSPLIT; ++ss) {
    __syncthreads();
    for (int i = t; i < CIT * LPAD; i += 256) xs[i] = 0.f;
    __syncthreads();
    const float* src = inp + (size_t)ss * CIT * LIN;
    for (int i = t; i < CIT * LIN; i += 256) {
      const int ci = i / LIN;
      const int l  = i & (LIN - 1);
      xs[ci * LPAD + PAD + l] = src[i];
    }
    __syncthreads();
    const float* wb = wbase + (size_t)ss * CIT * K;
    for (int ci = 0; ci < CIT; ++ci) {
      const float* xr = xs + ci * LPAD + 2 * j;
      const float* wr = wb + (size_t)ci * K;
      float xa = xr[0];
      for (int dk = 0; dk < K; ++dk) {
        const float xb = xr[dk + 1];
#pragma unroll
        for (int n = 0; n < NCO; ++n) {
          const float w = wr[(size_t)n * (CI * K) + dk];
          acc0[n] = fmaf(w, xa, acc0[n]);
          acc1[n] = fmaf(w, xb, acc1[n]);
        }
        xa = xb;
      }
    }
  }

  float* orow = out + (size_t)p * CO * LOUT;
#pragma unroll
  for (int n = 0; n < NCO; ++n) {
    const int co = co0 + n;
    const int pe = e * CO + co;
    const float s   = eg[pe] * rsqrtf(ev[pe] + BN_EPS);
    const float off = fmaf(eb[pe] - em[pe], s, ebb[pe]);
    const float y0 = fmaxf(fmaf(acc0[n], s, off), 0.f);
    const float y1 = fmaxf(fmaf(acc1[n], s, off), 0.f);
    orow[(size_t)co * LOUT + j] = fmaxf(y0, y1);
  }
}

// ---------------------------------------------------------------------------
// Kernel D1: global mean over L (=32) + gate-weighted combine of the two
// slots per sample. grid = 64 samples.
// ---------------------------------------------------------------------------
__global__ __launch_bounds__(256) void combine_kernel(
    const float* __restrict__ out4, const float* __restrict__ pair_g,
    float* __restrict__ g) {
  const int b = blockIdx.x, t = threadIdx.x;
  const float g0 = pair_g[2 * b], g1 = pair_g[2 * b + 1];
  const float* a0 = out4 + (size_t)(2 * b) * 512 * 32;
  const float* a1 = out4 + (size_t)(2 * b + 1) * 512 * 32;
  for (int c = t; c < 512; c += 256) {
    float s0 = 0.f, s1 = 0.f;
    for (int jj = 0; jj < 32; ++jj) {
      s0 += a0[c * 32 + jj];
      s1 += a1[c * 32 + jj];
    }
    g[b * 512 + c] = (g0 * s0 + g1 * s1) * (1.f / 32.f);
  }
}

// ---------------------------------------------------------------------------
// Kernel D2: FC head (512->256 relu ->64 relu ->5). One block per sample.
// ---------------------------------------------------------------------------
__global__ __launch_bounds__(256) void head_kernel(
    const float* __restrict__ g, const float* __restrict__ w1,
    const float* __restrict__ b1, const float* __restrict__ w2,
    const float* __restrict__ b2, const float* __restrict__ w3,
    const float* __restrict__ b3, float* __restrict__ out) {
  __shared__ float gl[512];
  __shared__ float h1[256];
  __shared__ float h2[64];
  const int b = blockIdx.x, t = threadIdx.x;
  for (int i = t; i < 512; i += 256) gl[i] = g[b * 512 + i];
  __syncthreads();
  {
    float a = b1[t];
    const float* wr = w1 + (size_t)t * 512;
    for (int k = 0; k < 512; ++k) a = fmaf(gl[k], wr[k], a);
    h1[t] = fmaxf(a, 0.f);
  }
  __syncthreads();
  if (t < 64) {
    float a = b2[t];
    const float* wr = w2 + (size_t)t * 256;
    for (int k = 0; k < 256; ++k) a = fmaf(h1[k], wr[k], a);
    h2[t] = fmaxf(a, 0.f);
  }
  __syncthreads();
  if (t < 5) {
    float a = b3[t];
    const float* wr = w3 + (size_t)t * 64;
    for (int k = 0; k < 64; ++k) a = fmaf(h2[k], wr[k], a);
    out[b * 5 + t] = a;
  }
}

// ---------------------------------------------------------------------------
extern "C" void kernel_launch(void* const* d_in, const int* in_sizes, int n_in,
                              void* d_out, int out_size, void* d_ws,
                              size_t ws_size, hipStream_t stream) {
  const float* x   = (const float*)d_in[0];
  const float* c1w = (const float*)d_in[1];
  const float* c1b = (const float*)d_in[2];
  const float* ew1 = (const float*)d_in[3];
  const float* eb1 = (const float*)d_in[4];
  const float* eg1 = (const float*)d_in[5];
  const float* ebb1= (const float*)d_in[6];
  const float* em1 = (const float*)d_in[7];
  const float* ev1 = (const float*)d_in[8];
  const float* ew2 = (const float*)d_in[9];
  const float* eb2 = (const float*)d_in[10];
  const float* eg2 = (const float*)d_in[11];
  const float* ebb2= (const float*)d_in[12];
  const float* em2 = (const float*)d_in[13];
  const float* ev2 = (const float*)d_in[14];
  const float* ew3 = (const float*)d_in[15];
  const float* eb3 = (const float*)d_in[16];
  const float* eg3 = (const float*)d_in[17];
  const float* ebb3= (const float*)d_in[18];
  const float* em3 = (const float*)d_in[19];
  const float* ev3 = (const float*)d_in[20];
  const float* ew4 = (const float*)d_in[21];
  const float* eb4 = (const float*)d_in[22];
  const float* eg4 = (const float*)d_in[23];
  const float* ebb4= (const float*)d_in[24];
  const float* em4 = (const float*)d_in[25];
  const float* ev4 = (const float*)d_in[26];
  const float* rw  = (const float*)d_in[27];
  const float* rb  = (const float*)d_in[28];
  const float* f1w = (const float*)d_in[29];
  const float* f1b = (const float*)d_in[30];
  const float* f2w = (const float*)d_in[31];
  const float* f2b = (const float*)d_in[32];
  const float* f3w = (const float*)d_in[33];
  const float* f3b = (const float*)d_in[34];
  float* out = (float*)d_out;

  // workspace layout (floats): h | pooled | pair_g | pair_e | bufA | bufB | g
  float* ws      = (float*)d_ws;
  float* h       = ws;                    // 64*16*512       = 524288
  float* pooled  = h + 524288;            // 64*16           = 1024
  float* pair_g  = pooled + 1024;         // 128
  int*   pair_e  = (int*)(pair_g + 128);  // 128
  float* bufA    = pair_g + 256;          // 128*64*256      = 2097152
  float* bufB    = bufA + 2097152;        // 128*128*128 ... = 2097152
  float* g       = bufB + 2097152;        // 64*512          = 32768

  conv1_kernel<<<64, 256, 0, stream>>>(x, c1w, c1b, h, pooled);
  router_kernel<<<1, 64, 0, stream>>>(pooled, rw, rb, pair_g, pair_e, out + 320);

  // block1: 16 -> 64, L 512 -> 256
  conv_block<16, 512, 3, 1, 64, 1, 8, 1, true>
      <<<dim3(8, 128), 256, 0, stream>>>(h, ew1, eb1, eg1, ebb1, em1, ev1,
                                         pair_e, bufA);
  // block2: 64 -> 128, L 256 -> 128
  conv_block<64, 256, 9, 4, 128, 2, 8, 2, false>
      <<<dim3(8, 128), 256, 0, stream>>>(bufA, ew2, eb2, eg2, ebb2, em2, ev2,
                                         pair_e, bufB);
  // block3: 128 -> 256, L 128 -> 64
  conv_block<128, 128, 11, 5, 256, 4, 8, 2, false>
      <<<dim3(8, 128), 256, 0, stream>>>(bufB, ew3, eb3, eg3, ebb3, em3, ev3,
                                         pair_e, bufA);
  // block4: 256 -> 512, L 64 -> 32
  conv_block<256, 64, 25, 12, 512, 8, 8, 2, false>
      <<<dim3(8, 128), 256, 0, stream>>>(bufA, ew4, eb4, eg4, ebb4, em4, ev4,
                                         pair_e, bufB);

  combine_kernel<<<64, 256, 0, stream>>>(bufB, pair_g, g);
  head_kernel<<<64, 256, 0, stream>>>(g, f1w, f1b, f2w, f2b, f3w, f3b, out);
}

// Round 2
// 1473.839 us; speedup vs baseline: 1.6322x; 1.6322x over previous
//
#include <hip/hip_runtime.h>
#include <math.h>

#define BN_EPS 1e-5f

// ---------------------------------------------------------------------------
// Kernel A: conv1 (k=3, pad=1, 1->16 ch) + ReLU, and channel means (pooled).
// ---------------------------------------------------------------------------
__global__ __launch_bounds__(256) void conv1_kernel(
    const float* __restrict__ x, const float* __restrict__ w,
    const float* __restrict__ bias, float* __restrict__ h,
    float* __restrict__ pooled) {
  __shared__ float xs[514];
  __shared__ float psum[256];
  const int b = blockIdx.x;
  const int t = threadIdx.x;
  for (int i = t; i < 512; i += 256) xs[i + 1] = x[b * 512 + i];
  if (t == 0) { xs[0] = 0.f; xs[513] = 0.f; }
  __syncthreads();
  const int c  = t >> 4;
  const int l0 = (t & 15) * 32;
  const float w0 = w[c * 3 + 0], w1 = w[c * 3 + 1], w2 = w[c * 3 + 2];
  const float bb = bias[c];
  float s = 0.f;
  float* hrow = h + ((size_t)b * 16 + c) * 512;
  for (int j = 0; j < 32; ++j) {
    const int l = l0 + j;
    float v = fmaf(w0, xs[l], fmaf(w1, xs[l + 1], fmaf(w2, xs[l + 2], bb)));
    v = fmaxf(v, 0.f);
    hrow[l] = v;
    s += v;
  }
  psum[t] = s;
  __syncthreads();
  if ((t & 15) == 0) {
    float tot = 0.f;
    for (int k = 0; k < 16; ++k) tot += psum[t + k];
    pooled[b * 16 + c] = tot * (1.f / 512.f);
  }
}

// ---------------------------------------------------------------------------
// Kernel B: router. softmax -> top2 -> renormalized gates + cv^2 scalar.
// ---------------------------------------------------------------------------
__global__ void router_kernel(const float* __restrict__ pooled,
                              const float* __restrict__ rw,
                              const float* __restrict__ rb,
                              float* __restrict__ pair_g,
                              int* __restrict__ pair_e,
                              float* __restrict__ out_cv) {
  __shared__ float probs_l[64][8];
  __shared__ float mp[8];
  const int t = threadIdx.x;
  {
    float pl[16];
    for (int c = 0; c < 16; ++c) pl[c] = pooled[t * 16 + c];
    float lg[8];
    float mx = -1e30f;
    for (int e = 0; e < 8; ++e) {
      float a = rb[e];
      for (int c = 0; c < 16; ++c) a = fmaf(pl[c], rw[e * 16 + c], a);
      lg[e] = a;
      mx = fmaxf(mx, a);
    }
    float sum = 0.f;
    for (int e = 0; e < 8; ++e) { lg[e] = expf(lg[e] - mx); sum += lg[e]; }
    const float inv = 1.f / sum;
    for (int e = 0; e < 8; ++e) { lg[e] *= inv; probs_l[t][e] = lg[e]; }
    int e1 = 0; float p1 = lg[0];
    for (int e = 1; e < 8; ++e) if (lg[e] > p1) { p1 = lg[e]; e1 = e; }
    int e2 = -1; float p2 = -1.f;
    for (int e = 0; e < 8; ++e) if (e != e1 && lg[e] > p2) { p2 = lg[e]; e2 = e; }
    const float gs = 1.f / (p1 + p2);
    pair_e[2 * t]     = e1; pair_g[2 * t]     = p1 * gs;
    pair_e[2 * t + 1] = e2; pair_g[2 * t + 1] = p2 * gs;
  }
  __syncthreads();
  if (t < 8) {
    float s = 0.f;
    for (int b = 0; b < 64; ++b) s += probs_l[b][t];
    mp[t] = s * (1.f / 64.f);
  }
  __syncthreads();
  if (t == 0) {
    float mean = 0.f;
    for (int e = 0; e < 8; ++e) mean += mp[e];
    mean *= (1.f / 8.f);
    float var = 0.f;
    for (int e = 0; e < 8; ++e) { const float d = mp[e] - mean; var = fmaf(d, d, var); }
    var *= (1.f / 7.f);
    const float cv = sqrtf(var) / (mean + 1e-10f);
    *out_cv = cv * cv;
  }
}

// ---------------------------------------------------------------------------
// Kernel C: expert conv block (conv K -> BN -> ReLU -> maxpool2), sparse over
// 128 (sample,slot) pairs. Block covers a 64-co x 64-pre-pool-position tile
// of one pair. grid.x = (CO/64)*(LIN/64), grid.y = 128.
//
// Per ci-chunk: stage x window [CIC][W_XP] and weights transposed to
// [ci][k][co+2pad] in LDS (coalesced global reads; 2-way LDS aliasing = free).
// Thread owns 2 co x 8 positions (16 acc); inner loop per (ci,dk) is
// 1 broadcast ds_read_b64 (weights) + 1 ds_read_b32 (slide) + 16 FMA.
// Epilogue: fused BN+ReLU+maxpool2, float4 stores.
// ---------------------------------------------------------------------------
template <int CI, int LIN, int K, int PAD, int CO, int CIC, bool IN_IS_H>
__global__ __launch_bounds__(256) void conv_block(
    const float* __restrict__ in, const float* __restrict__ ew,
    const float* __restrict__ eb, const float* __restrict__ eg,
    const float* __restrict__ ebb, const float* __restrict__ em,
    const float* __restrict__ ev, const int* __restrict__ pair_e,
    float* __restrict__ out) {
  constexpr int JT_N = LIN / 64;          // position tiles
  constexpr int W_X  = 64 + K - 1;        // x window width
  constexpr int W_XP = (W_X + 3) & ~3;    // row-aligned to 16B
  constexpr int WROW = 66;                // 64 co + 2 pad
  constexpr int NCH  = CI / CIC;
  constexpr int LOUT = LIN / 2;

  __shared__ __align__(16) float xs[CIC * W_XP];
  __shared__ __align__(16) float wls[CIC * K * WROW];

  const int p  = blockIdx.y;
  const int t  = threadIdx.x;
  const int e  = pair_e[p];
  const int jt = blockIdx.x % JT_N;       // position tile (x64)
  const int ct = blockIdx.x / JT_N;       // co tile (x64)
  const int co0 = ct * 64;

  const float* inp = IN_IS_H ? (in + (size_t)(p >> 1) * CI * LIN)
                             : (in + (size_t)p * CI * LIN);
  const int cg = t & 31;                  // co pair group
  const int jg = t >> 5;                  // position group (8 wide)

  float acc0[8], acc1[8];
#pragma unroll
  for (int u = 0; u < 8; ++u) { acc0[u] = 0.f; acc1[u] = 0.f; }

  const int gx0 = jt * 64 - PAD;          // global x index of local w=0

  for (int ch = 0; ch < NCH; ++ch) {
    const int ci0 = ch * CIC;
    __syncthreads();
    // stage x window (zero-padded)
    for (int i = t; i < CIC * W_XP; i += 256) {
      const int ci = i / W_XP, w = i % W_XP;
      const int gi = gx0 + w;
      float v = 0.f;
      if (w < W_X && gi >= 0 && gi < LIN)
        v = inp[(size_t)(ci0 + ci) * LIN + gi];
      xs[i] = v;
    }
    // stage weights, transposed to [ci][k][co]
    for (int i = t; i < CIC * K * 64; i += 256) {
      const int co = i / (CIC * K);
      const int r  = i % (CIC * K);
      const int ci = r / K, k = r % K;
      wls[(ci * K + k) * WROW + co] =
          ew[(((size_t)e * CO + co0 + co) * CI + (ci0 + ci)) * K + k];
    }
    __syncthreads();
    // compute
    for (int ci = 0; ci < CIC; ++ci) {
      const float* xrow = xs + ci * W_XP + jg * 8;
      const float* wrow = wls + ci * K * WROW + 2 * cg;
      float xw[8];
      {
        const float4 a = *(const float4*)(xrow);
        const float4 b = *(const float4*)(xrow + 4);
        xw[0] = a.x; xw[1] = a.y; xw[2] = a.z; xw[3] = a.w;
        xw[4] = b.x; xw[5] = b.y; xw[6] = b.z; xw[7] = b.w;
      }
#pragma unroll
      for (int dk = 0; dk < K; ++dk) {
        const float2 wv = *(const float2*)(wrow + dk * WROW);
#pragma unroll
        for (int u = 0; u < 8; ++u) {
          const float xv = xw[(dk + u) & 7];
          acc0[u] = fmaf(wv.x, xv, acc0[u]);
          acc1[u] = fmaf(wv.y, xv, acc1[u]);
        }
        if (dk + 1 < K) xw[dk & 7] = xrow[dk + 8];
      }
    }
  }

  // epilogue: BN + ReLU + maxpool2, 4 pooled outputs per co
  const int j0 = jt * 32 + jg * 4;
#pragma unroll
  for (int n = 0; n < 2; ++n) {
    const float* acc = n ? acc1 : acc0;
    const int co = co0 + 2 * cg + n;
    const int pe = e * CO + co;
    const float s   = eg[pe] * rsqrtf(ev[pe] + BN_EPS);
    const float off = fmaf(eb[pe] - em[pe], s, ebb[pe]);
    float4 o;
    {
      const float y0 = fmaxf(fmaf(acc[0], s, off), 0.f);
      const float y1 = fmaxf(fmaf(acc[1], s, off), 0.f);
      o.x = fmaxf(y0, y1);
    }
    {
      const float y0 = fmaxf(fmaf(acc[2], s, off), 0.f);
      const float y1 = fmaxf(fmaf(acc[3], s, off), 0.f);
      o.y = fmaxf(y0, y1);
    }
    {
      const float y0 = fmaxf(fmaf(acc[4], s, off), 0.f);
      const float y1 = fmaxf(fmaf(acc[5], s, off), 0.f);
      o.z = fmaxf(y0, y1);
    }
    {
      const float y0 = fmaxf(fmaf(acc[6], s, off), 0.f);
      const float y1 = fmaxf(fmaf(acc[7], s, off), 0.f);
      o.w = fmaxf(y0, y1);
    }
    *(float4*)(out + ((size_t)p * CO + co) * LOUT + j0) = o;
  }
}

// ---------------------------------------------------------------------------
// Kernel D1: global mean over L + gate-weighted combine.
// ---------------------------------------------------------------------------
__global__ __launch_bounds__(256) void combine_kernel(
    const float* __restrict__ out4, const float* __restrict__ pair_g,
    float* __restrict__ g) {
  const int b = blockIdx.x, t = threadIdx.x;
  const float g0 = pair_g[2 * b], g1 = pair_g[2 * b + 1];
  const float* a0 = out4 + (size_t)(2 * b) * 512 * 32;
  const float* a1 = out4 + (size_t)(2 * b + 1) * 512 * 32;
  for (int c = t; c < 512; c += 256) {
    float s0 = 0.f, s1 = 0.f;
    for (int jj = 0; jj < 32; ++jj) {
      s0 += a0[c * 32 + jj];
      s1 += a1[c * 32 + jj];
    }
    g[b * 512 + c] = (g0 * s0 + g1 * s1) * (1.f / 32.f);
  }
}

// ---------------------------------------------------------------------------
// Kernel D2: FC head (512->256 relu ->64 relu ->5). One block per sample.
// ---------------------------------------------------------------------------
__global__ __launch_bounds__(256) void head_kernel(
    const float* __restrict__ g, const float* __restrict__ w1,
    const float* __restrict__ b1, const float* __restrict__ w2,
    const float* __restrict__ b2, const float* __restrict__ w3,
    const float* __restrict__ b3, float* __restrict__ out) {
  __shared__ float gl[512];
  __shared__ float h1[256];
  __shared__ float h2[64];
  const int b = blockIdx.x, t = threadIdx.x;
  for (int i = t; i < 512; i += 256) gl[i] = g[b * 512 + i];
  __syncthreads();
  {
    float a = b1[t];
    const float* wr = w1 + (size_t)t * 512;
    for (int k = 0; k < 512; ++k) a = fmaf(gl[k], wr[k], a);
    h1[t] = fmaxf(a, 0.f);
  }
  __syncthreads();
  if (t < 64) {
    float a = b2[t];
    const float* wr = w2 + (size_t)t * 256;
    for (int k = 0; k < 256; ++k) a = fmaf(h1[k], wr[k], a);
    h2[t] = fmaxf(a, 0.f);
  }
  __syncthreads();
  if (t < 5) {
    float a = b3[t];
    const float* wr = w3 + (size_t)t * 64;
    for (int k = 0; k < 64; ++k) a = fmaf(h2[k], wr[k], a);
    out[b * 5 + t] = a;
  }
}

// ---------------------------------------------------------------------------
extern "C" void kernel_launch(void* const* d_in, const int* in_sizes, int n_in,
                              void* d_out, int out_size, void* d_ws,
                              size_t ws_size, hipStream_t stream) {
  const float* x   = (const float*)d_in[0];
  const float* c1w = (const float*)d_in[1];
  const float* c1b = (const float*)d_in[2];
  const float* ew1 = (const float*)d_in[3];
  const float* eb1 = (const float*)d_in[4];
  const float* eg1 = (const float*)d_in[5];
  const float* ebb1= (const float*)d_in[6];
  const float* em1 = (const float*)d_in[7];
  const float* ev1 = (const float*)d_in[8];
  const float* ew2 = (const float*)d_in[9];
  const float* eb2 = (const float*)d_in[10];
  const float* eg2 = (const float*)d_in[11];
  const float* ebb2= (const float*)d_in[12];
  const float* em2 = (const float*)d_in[13];
  const float* ev2 = (const float*)d_in[14];
  const float* ew3 = (const float*)d_in[15];
  const float* eb3 = (const float*)d_in[16];
  const float* eg3 = (const float*)d_in[17];
  const float* ebb3= (const float*)d_in[18];
  const float* em3 = (const float*)d_in[19];
  const float* ev3 = (const float*)d_in[20];
  const float* ew4 = (const float*)d_in[21];
  const float* eb4 = (const float*)d_in[22];
  const float* eg4 = (const float*)d_in[23];
  const float* ebb4= (const float*)d_in[24];
  const float* em4 = (const float*)d_in[25];
  const float* ev4 = (const float*)d_in[26];
  const float* rw  = (const float*)d_in[27];
  const float* rb  = (const float*)d_in[28];
  const float* f1w = (const float*)d_in[29];
  const float* f1b = (const float*)d_in[30];
  const float* f2w = (const float*)d_in[31];
  const float* f2b = (const float*)d_in[32];
  const float* f3w = (const float*)d_in[33];
  const float* f3b = (const float*)d_in[34];
  float* out = (float*)d_out;

  // workspace layout (floats): h | pooled | pair_g | pair_e | bufA | bufB | g
  float* ws      = (float*)d_ws;
  float* h       = ws;                    // 64*16*512       = 524288
  float* pooled  = h + 524288;            // 64*16           = 1024
  float* pair_g  = pooled + 1024;         // 128
  int*   pair_e  = (int*)(pair_g + 128);  // 128
  float* bufA    = pair_g + 256;          // 2097152
  float* bufB    = bufA + 2097152;        // 2097152
  float* g       = bufB + 2097152;        // 32768

  conv1_kernel<<<64, 256, 0, stream>>>(x, c1w, c1b, h, pooled);
  router_kernel<<<1, 64, 0, stream>>>(pooled, rw, rb, pair_g, pair_e, out + 320);

  // block1: 16 -> 64, L 512 -> 256   grid.x = (64/64)*(512/64) = 8
  conv_block<16, 512, 3, 1, 64, 16, true>
      <<<dim3(8, 128), 256, 0, stream>>>(h, ew1, eb1, eg1, ebb1, em1, ev1,
                                         pair_e, bufA);
  // block2: 64 -> 128, L 256 -> 128  grid.x = 2*4 = 8
  conv_block<64, 256, 9, 4, 128, 8, false>
      <<<dim3(8, 128), 256, 0, stream>>>(bufA, ew2, eb2, eg2, ebb2, em2, ev2,
                                         pair_e, bufB);
  // block3: 128 -> 256, L 128 -> 64  grid.x = 4*2 = 8
  conv_block<128, 128, 11, 5, 256, 8, false>
      <<<dim3(8, 128), 256, 0, stream>>>(bufB, ew3, eb3, eg3, ebb3, em3, ev3,
                                         pair_e, bufA);
  // block4: 256 -> 512, L 64 -> 32   grid.x = 8*1 = 8
  conv_block<256, 64, 25, 12, 512, 4, false>
      <<<dim3(8, 128), 256, 0, stream>>>(bufA, ew4, eb4, eg4, ebb4, em4, ev4,
                                         pair_e, bufB);

  combine_kernel<<<64, 256, 0, stream>>>(bufB, pair_g, g);
  head_kernel<<<64, 256, 0, stream>>>(g, f1w, f1b, f2w, f2b, f3w, f3b, out);
}

// Round 3
// 697.625 us; speedup vs baseline: 3.4482x; 2.1127x over previous
//
#include <hip/hip_runtime.h>
#include <math.h>

#define BN_EPS 1e-5f

typedef _Float16 half8 __attribute__((ext_vector_type(8)));
typedef float floatx4 __attribute__((ext_vector_type(4)));

// ---------------------------------------------------------------------------
// Kernel A: conv1 (k=3, pad=1, 1->16 ch) + ReLU, and channel means (pooled).
// ---------------------------------------------------------------------------
__global__ __launch_bounds__(256) void conv1_kernel(
    const float* __restrict__ x, const float* __restrict__ w,
    const float* __restrict__ bias, float* __restrict__ h,
    float* __restrict__ pooled) {
  __shared__ float xs[514];
  __shared__ float psum[256];
  const int b = blockIdx.x;
  const int t = threadIdx.x;
  for (int i = t; i < 512; i += 256) xs[i + 1] = x[b * 512 + i];
  if (t == 0) { xs[0] = 0.f; xs[513] = 0.f; }
  __syncthreads();
  const int c  = t >> 4;
  const int l0 = (t & 15) * 32;
  const float w0 = w[c * 3 + 0], w1 = w[c * 3 + 1], w2 = w[c * 3 + 2];
  const float bb = bias[c];
  float s = 0.f;
  float* hrow = h + ((size_t)b * 16 + c) * 512;
  for (int j = 0; j < 32; ++j) {
    const int l = l0 + j;
    float v = fmaf(w0, xs[l], fmaf(w1, xs[l + 1], fmaf(w2, xs[l + 2], bb)));
    v = fmaxf(v, 0.f);
    hrow[l] = v;
    s += v;
  }
  psum[t] = s;
  __syncthreads();
  if ((t & 15) == 0) {
    float tot = 0.f;
    for (int k = 0; k < 16; ++k) tot += psum[t + k];
    pooled[b * 16 + c] = tot * (1.f / 512.f);
  }
}

// ---------------------------------------------------------------------------
// Kernel B: router. softmax -> top2 -> renormalized gates + cv^2 scalar.
// ---------------------------------------------------------------------------
__global__ void router_kernel(const float* __restrict__ pooled,
                              const float* __restrict__ rw,
                              const float* __restrict__ rb,
                              float* __restrict__ pair_g,
                              int* __restrict__ pair_e,
                              float* __restrict__ out_cv) {
  __shared__ float probs_l[64][8];
  __shared__ float mp[8];
  const int t = threadIdx.x;
  {
    float pl[16];
    for (int c = 0; c < 16; ++c) pl[c] = pooled[t * 16 + c];
    float lg[8];
    float mx = -1e30f;
    for (int e = 0; e < 8; ++e) {
      float a = rb[e];
      for (int c = 0; c < 16; ++c) a = fmaf(pl[c], rw[e * 16 + c], a);
      lg[e] = a;
      mx = fmaxf(mx, a);
    }
    float sum = 0.f;
    for (int e = 0; e < 8; ++e) { lg[e] = expf(lg[e] - mx); sum += lg[e]; }
    const float inv = 1.f / sum;
    for (int e = 0; e < 8; ++e) { lg[e] *= inv; probs_l[t][e] = lg[e]; }
    int e1 = 0; float p1 = lg[0];
    for (int e = 1; e < 8; ++e) if (lg[e] > p1) { p1 = lg[e]; e1 = e; }
    int e2 = -1; float p2 = -1.f;
    for (int e = 0; e < 8; ++e) if (e != e1 && lg[e] > p2) { p2 = lg[e]; e2 = e; }
    const float gs = 1.f / (p1 + p2);
    pair_e[2 * t]     = e1; pair_g[2 * t]     = p1 * gs;
    pair_e[2 * t + 1] = e2; pair_g[2 * t + 1] = p2 * gs;
  }
  __syncthreads();
  if (t < 8) {
    float s = 0.f;
    for (int b = 0; b < 64; ++b) s += probs_l[b][t];
    mp[t] = s * (1.f / 64.f);
  }
  __syncthreads();
  if (t == 0) {
    float mean = 0.f;
    for (int e = 0; e < 8; ++e) mean += mp[e];
    mean *= (1.f / 8.f);
    float var = 0.f;
    for (int e = 0; e < 8; ++e) { const float d = mp[e] - mean; var = fmaf(d, d, var); }
    var *= (1.f / 7.f);
    const float cv = sqrtf(var) / (mean + 1e-10f);
    *out_cv = cv * cv;
  }
}

// ---------------------------------------------------------------------------
// Weight repack: ew[e][co][ci][k] fp32 -> wr[e][k][co][ci] fp16.
// Thread handles one (e,co,ci, k-octet): 8 consecutive-k reads (contiguous),
// 8 scattered 2B writes that are coalesced across the ci-fastest lane dim.
// ---------------------------------------------------------------------------
template <int CI, int K, int CO>
__global__ __launch_bounds__(256) void repack_kernel(
    const float* __restrict__ ew, _Float16* __restrict__ wr) {
  constexpr int KOCT = (K + 7) / 8;
  const int total = 8 * CO * KOCT * CI;
  int tid = blockIdx.x * 256 + threadIdx.x;
  if (tid >= total) return;
  const int ci = tid % CI;
  int r = tid / CI;
  const int o = r % KOCT; r /= KOCT;
  const int co = r % CO;
  const int e = r / CO;
  const float* s = ew + ((size_t)(e * CO + co) * CI + ci) * K + o * 8;
#pragma unroll
  for (int j = 0; j < 8; ++j) {
    const int k = o * 8 + j;
    if (k < K)
      wr[((size_t)(e * K + k) * CO + co) * CI + ci] = (_Float16)s[j];
  }
}

// ---------------------------------------------------------------------------
// Block1 (fp32 vector conv, 16->64ch, L512->256): old-style kernel, but
// epilogue writes transposed fp16 [pair][xp][co] for the MFMA consumer.
// ---------------------------------------------------------------------------
__global__ __launch_bounds__(256) void conv_block1(
    const float* __restrict__ in, const float* __restrict__ ew,
    const float* __restrict__ eb, const float* __restrict__ eg,
    const float* __restrict__ ebb, const float* __restrict__ em,
    const float* __restrict__ ev, const int* __restrict__ pair_e,
    _Float16* __restrict__ out) {
  constexpr int CI = 16, LIN = 512, K = 3, PAD = 1, CO = 64;
  constexpr int JT_N = LIN / 64;   // 8
  constexpr int W_X  = 64 + K - 1; // 66
  constexpr int W_XP = 68;
  constexpr int WROW = 66;
  __shared__ __align__(16) float xs[CI * W_XP];
  __shared__ __align__(16) float wls[CI * K * WROW];

  const int p  = blockIdx.y;
  const int t  = threadIdx.x;
  const int e  = pair_e[p];
  const int jt = blockIdx.x;       // position tile
  const float* inp = in + (size_t)(p >> 1) * CI * LIN;
  const int cg = t & 31;
  const int jg = t >> 5;

  float acc0[8], acc1[8];
#pragma unroll
  for (int u = 0; u < 8; ++u) { acc0[u] = 0.f; acc1[u] = 0.f; }
  const int gx0 = jt * 64 - PAD;

  for (int i = t; i < CI * W_XP; i += 256) {
    const int ci = i / W_XP, w = i % W_XP;
    const int gi = gx0 + w;
    float v = 0.f;
    if (w < W_X && gi >= 0 && gi < LIN) v = inp[(size_t)ci * LIN + gi];
    xs[i] = v;
  }
  for (int i = t; i < CI * K * 64; i += 256) {
    const int co = i / (CI * K);
    const int r  = i % (CI * K);
    const int ci = r / K, k = r % K;
    wls[(ci * K + k) * WROW + co] =
        ew[(((size_t)e * CO + co) * CI + ci) * K + k];
  }
  __syncthreads();
  for (int ci = 0; ci < CI; ++ci) {
    const float* xrow = xs + ci * W_XP + jg * 8;
    const float* wrow = wls + ci * K * WROW + 2 * cg;
    float xw[8];
    {
      const float4 a = *(const float4*)(xrow);
      const float4 b = *(const float4*)(xrow + 4);
      xw[0] = a.x; xw[1] = a.y; xw[2] = a.z; xw[3] = a.w;
      xw[4] = b.x; xw[5] = b.y; xw[6] = b.z; xw[7] = b.w;
    }
#pragma unroll
    for (int dk = 0; dk < K; ++dk) {
      const float2 wv = *(const float2*)(wrow + dk * WROW);
#pragma unroll
      for (int u = 0; u < 8; ++u) {
        const float xv = xw[(dk + u) & 7];
        acc0[u] = fmaf(wv.x, xv, acc0[u]);
        acc1[u] = fmaf(wv.y, xv, acc1[u]);
      }
      if (dk + 1 < K) xw[dk & 7] = xrow[dk + 8];
    }
  }

  const int j0 = jt * 32 + jg * 4;  // pooled position base
#pragma unroll
  for (int n = 0; n < 2; ++n) {
    const float* acc = n ? acc1 : acc0;
    const int co = 2 * cg + n;
    const int pe = e * CO + co;
    const float s   = eg[pe] * rsqrtf(ev[pe] + BN_EPS);
    const float off = fmaf(eb[pe] - em[pe], s, ebb[pe]);
#pragma unroll
    for (int q = 0; q < 4; ++q) {
      const float y0 = fmaxf(fmaf(acc[2 * q], s, off), 0.f);
      const float y1 = fmaxf(fmaf(acc[2 * q + 1], s, off), 0.f);
      out[((size_t)p * 256 + j0 + q) * CO + co] = (_Float16)fmaxf(y0, y1);
    }
  }
}

// ---------------------------------------------------------------------------
// MFMA conv block (fp16 in / fp16 out, fp32 acc): conv K -> BN -> ReLU ->
// maxpool2, over 128 (sample,slot) pairs.
//   D[co][x] = sum_dk sum_ci W[e][dk][co][ci] * X[p][x+dk-PAD][ci]
// Activations layout [pair][x][CI] fp16; weights repacked [e][dk][co][ci].
// Block: 256 thr = 4 waves (WM x WN), wave-tile 64co x 64x of 16x16x32 MFMAs.
// B-window (x rows for all dk of a ci-chunk) staged once per ci-chunk;
// A (per-dk weight tile) double-buffered; 1 barrier per dk.
// LDS rows padded to 40 halfs (80 B) -> <=2-way bank aliasing (free).
// ---------------------------------------------------------------------------
template <int CI, int K, int PAD, int CO, int LIN, int WM, int WN>
__global__ __launch_bounds__(256) void mfma_conv(
    const _Float16* __restrict__ xin, const _Float16* __restrict__ wr,
    const float* __restrict__ eb, const float* __restrict__ eg,
    const float* __restrict__ ebb, const float* __restrict__ em,
    const float* __restrict__ ev, const int* __restrict__ pair_e,
    _Float16* __restrict__ out) {
  constexpr int BM  = WM * 64;
  constexpr int XN  = WN * 64;
  constexpr int XWR = XN + K - 1;
  constexpr int NC  = CI / 32;
  constexpr int XT  = LIN / XN;
  constexpr int LH  = 40;  // LDS row stride in halfs (80 B)

  __shared__ _Float16 Ash[2 * BM * LH];
  __shared__ _Float16 Bsh[XWR * LH];
  __shared__ float sc[BM];
  __shared__ float of[BM];

  const int p  = blockIdx.y;
  const int t  = threadIdx.x;
  const int e  = pair_e[p];
  const int xt = blockIdx.x % XT;
  const int ct = blockIdx.x / XT;
  const int co0 = ct * BM;
  const int x0  = xt * XN;

  const int lane = t & 63;
  const int wave = t >> 6;
  const int wm = wave / WN;
  const int wn = wave % WN;
  const int lm = lane & 15;
  const int q  = lane >> 4;

  // BN scale/offset per co
  for (int i = t; i < BM; i += 256) {
    const int pe = e * CO + co0 + i;
    const float s = eg[pe] * rsqrtf(ev[pe] + BN_EPS);
    sc[i] = s;
    of[i] = fmaf(eb[pe] - em[pe], s, ebb[pe]);
  }

  floatx4 acc[4][4];
#pragma unroll
  for (int a = 0; a < 4; ++a)
#pragma unroll
    for (int b = 0; b < 4; ++b) acc[a][b] = (floatx4){0.f, 0.f, 0.f, 0.f};

  const _Float16* xp_base = xin + (size_t)p * LIN * CI;

  // --- staging helpers (lambdas) ---
  auto stage_B = [&](int cic) {
    const _Float16* src = xp_base + cic * 32;
    for (int c = t; c < XWR * 4; c += 256) {
      const int row = c >> 2, qq = c & 3;
      const int gx = x0 - PAD + row;
      uint4 v = {0u, 0u, 0u, 0u};
      if (gx >= 0 && gx < LIN)
        v = *(const uint4*)(src + (size_t)gx * CI + qq * 8);
      *(uint4*)(Bsh + row * LH + qq * 8) = v;
    }
  };
  auto stage_A = [&](int cic, int dk, int buf) {
    _Float16* dst = Ash + buf * (BM * LH);
    const _Float16* src =
        wr + ((size_t)(e * K + dk) * CO + co0) * CI + cic * 32;
    for (int c = t; c < BM * 4; c += 256) {
      const int co = c >> 2, qq = c & 3;
      uint4 v = *(const uint4*)(src + (size_t)co * CI + qq * 8);
      *(uint4*)(dst + co * LH + qq * 8) = v;
    }
  };

  stage_B(0);
  stage_A(0, 0, 0);
  __syncthreads();

  int cur = 0;
  for (int cic = 0; cic < NC; ++cic) {
    for (int dk = 0; dk < K; ++dk) {
      if (dk + 1 < K) stage_A(cic, dk + 1, cur ^ 1);
      else if (cic + 1 < NC) stage_A(cic + 1, 0, cur ^ 1);
      // MFMA phase on buffer `cur`
      {
        const _Float16* Ab = Ash + cur * (BM * LH);
        half8 af[4], bf[4];
#pragma unroll
        for (int mt = 0; mt < 4; ++mt)
          af[mt] = *(const half8*)(Ab + (wm * 64 + mt * 16 + lm) * LH + q * 8);
#pragma unroll
        for (int nt = 0; nt < 4; ++nt)
          bf[nt] = *(const half8*)(Bsh + (wn * 64 + nt * 16 + lm + dk) * LH + q * 8);
#pragma unroll
        for (int mt = 0; mt < 4; ++mt)
#pragma unroll
          for (int nt = 0; nt < 4; ++nt)
            acc[mt][nt] = __builtin_amdgcn_mfma_f32_16x16x32_f16(
                af[mt], bf[nt], acc[mt][nt], 0, 0, 0);
      }
      __syncthreads();
      cur ^= 1;
    }
    if (cic + 1 < NC) {
      stage_B(cic + 1);
      __syncthreads();
    }
  }

  // Epilogue: BN + ReLU, maxpool2 via shfl_xor(1) (x pairs are adjacent
  // lanes in the C layout: col = lane&15 = x, row = quad*4+reg = co).
#pragma unroll
  for (int mt = 0; mt < 4; ++mt) {
#pragma unroll
    for (int nt = 0; nt < 4; ++nt) {
      union { _Float16 h[4]; uint2 u; } pk;
#pragma unroll
      for (int r = 0; r < 4; ++r) {
        const int co_l = wm * 64 + mt * 16 + q * 4 + r;
        float y = fmaxf(fmaf(acc[mt][nt][r], sc[co_l], of[co_l]), 0.f);
        const float yp = __shfl_xor(y, 1, 64);
        pk.h[r] = (_Float16)fmaxf(y, yp);
      }
      if ((lane & 1) == 0) {
        const int xg = x0 + wn * 64 + nt * 16 + lm;
        const int xp = xg >> 1;
        const int cob = co0 + wm * 64 + mt * 16 + q * 4;
        *(uint2*)(out + ((size_t)p * (LIN / 2) + xp) * CO + cob) = pk.u;
      }
    }
  }
}

// ---------------------------------------------------------------------------
// Combine: mean over 32 positions of block4 output [p][xp][512] fp16,
// gate-weighted sum of the two slots -> g[b][512] fp32.
// ---------------------------------------------------------------------------
__global__ __launch_bounds__(256) void combine_kernel(
    const _Float16* __restrict__ out4, const float* __restrict__ pair_g,
    float* __restrict__ g) {
  const int b = blockIdx.x, t = threadIdx.x;
  const float g0 = pair_g[2 * b], g1 = pair_g[2 * b + 1];
  const _Float16* a0 = out4 + (size_t)(2 * b) * 32 * 512;
  const _Float16* a1 = out4 + (size_t)(2 * b + 1) * 32 * 512;
  for (int c = t; c < 512; c += 256) {
    float s0 = 0.f, s1 = 0.f;
    for (int jj = 0; jj < 32; ++jj) {
      s0 += (float)a0[jj * 512 + c];
      s1 += (float)a1[jj * 512 + c];
    }
    g[b * 512 + c] = (g0 * s0 + g1 * s1) * (1.f / 32.f);
  }
}

// ---------------------------------------------------------------------------
// FC head (512->256 relu ->64 relu ->5). One block per sample.
// ---------------------------------------------------------------------------
__global__ __launch_bounds__(256) void head_kernel(
    const float* __restrict__ g, const float* __restrict__ w1,
    const float* __restrict__ b1, const float* __restrict__ w2,
    const float* __restrict__ b2, const float* __restrict__ w3,
    const float* __restrict__ b3, float* __restrict__ out) {
  __shared__ float gl[512];
  __shared__ float h1[256];
  __shared__ float h2[64];
  const int b = blockIdx.x, t = threadIdx.x;
  for (int i = t; i < 512; i += 256) gl[i] = g[b * 512 + i];
  __syncthreads();
  {
    float a = b1[t];
    const float* wr = w1 + (size_t)t * 512;
    for (int k = 0; k < 512; ++k) a = fmaf(gl[k], wr[k], a);
    h1[t] = fmaxf(a, 0.f);
  }
  __syncthreads();
  if (t < 64) {
    float a = b2[t];
    const float* wr = w2 + (size_t)t * 256;
    for (int k = 0; k < 256; ++k) a = fmaf(h1[k], wr[k], a);
    h2[t] = fmaxf(a, 0.f);
  }
  __syncthreads();
  if (t < 5) {
    float a = b3[t];
    const float* wr = w3 + (size_t)t * 64;
    for (int k = 0; k < 64; ++k) a = fmaf(h2[k], wr[k], a);
    out[b * 5 + t] = a;
  }
}

// ---------------------------------------------------------------------------
extern "C" void kernel_launch(void* const* d_in, const int* in_sizes, int n_in,
                              void* d_out, int out_size, void* d_ws,
                              size_t ws_size, hipStream_t stream) {
  const float* x   = (const float*)d_in[0];
  const float* c1w = (const float*)d_in[1];
  const float* c1b = (const float*)d_in[2];
  const float* ew1 = (const float*)d_in[3];
  const float* eb1 = (const float*)d_in[4];
  const float* eg1 = (const float*)d_in[5];
  const float* ebb1= (const float*)d_in[6];
  const float* em1 = (const float*)d_in[7];
  const float* ev1 = (const float*)d_in[8];
  const float* ew2 = (const float*)d_in[9];
  const float* eb2 = (const float*)d_in[10];
  const float* eg2 = (const float*)d_in[11];
  const float* ebb2= (const float*)d_in[12];
  const float* em2 = (const float*)d_in[13];
  const float* ev2 = (const float*)d_in[14];
  const float* ew3 = (const float*)d_in[15];
  const float* eb3 = (const float*)d_in[16];
  const float* eg3 = (const float*)d_in[17];
  const float* ebb3= (const float*)d_in[18];
  const float* em3 = (const float*)d_in[19];
  const float* ev3 = (const float*)d_in[20];
  const float* ew4 = (const float*)d_in[21];
  const float* eb4 = (const float*)d_in[22];
  const float* eg4 = (const float*)d_in[23];
  const float* ebb4= (const float*)d_in[24];
  const float* em4 = (const float*)d_in[25];
  const float* ev4 = (const float*)d_in[26];
  const float* rw  = (const float*)d_in[27];
  const float* rb  = (const float*)d_in[28];
  const float* f1w = (const float*)d_in[29];
  const float* f1b = (const float*)d_in[30];
  const float* f2w = (const float*)d_in[31];
  const float* f2b = (const float*)d_in[32];
  const float* f3w = (const float*)d_in[33];
  const float* f3b = (const float*)d_in[34];
  float* out = (float*)d_out;

  // workspace layout (float units for offsets; fp16 regions aliased)
  float* ws      = (float*)d_ws;
  float* h       = ws;                       // 524288 f32
  float* pooled  = h + 524288;               // 1024
  float* pair_g  = pooled + 1024;            // 128
  int*   pair_e  = (int*)(pair_g + 128);     // 128
  _Float16* o1   = (_Float16*)(ws + 525568);   // 128*256*64  = 2,097,152 h
  _Float16* o2   = o1 + 2097152;               // 128*128*128 h
  _Float16* o3   = o2 + 2097152;               // 128*64*256  h
  _Float16* o4   = o3 + 2097152;               // 128*32*512  h
  _Float16* w2r  = o4 + 2097152;               // 8*9*128*64   = 589,824 h
  _Float16* w3r  = w2r + 589824;               // 8*11*256*128 = 2,883,584 h
  _Float16* w4r  = w3r + 2883584;              // 8*25*512*256 = 26,214,400 h
  float* g       = (float*)(w4r + 26214400);   // 64*512 f32

  conv1_kernel<<<64, 256, 0, stream>>>(x, c1w, c1b, h, pooled);
  router_kernel<<<1, 64, 0, stream>>>(pooled, rw, rb, pair_g, pair_e, out + 320);

  // weight repacks: [e][co][ci][k] fp32 -> [e][k][co][ci] fp16
  repack_kernel<64, 9, 128><<<(8 * 128 * 2 * 64 + 255) / 256, 256, 0, stream>>>(ew2, w2r);
  repack_kernel<128, 11, 256><<<(8 * 256 * 2 * 128 + 255) / 256, 256, 0, stream>>>(ew3, w3r);
  repack_kernel<256, 25, 512><<<(8 * 512 * 4 * 256 + 255) / 256, 256, 0, stream>>>(ew4, w4r);

  // block1: fp32 vector conv, 16->64, L512->256, fp16 transposed out
  conv_block1<<<dim3(8, 128), 256, 0, stream>>>(h, ew1, eb1, eg1, ebb1, em1,
                                                ev1, pair_e, o1);
  // block2: 64->128, L256->128   (2 blocks x 128 pairs)
  mfma_conv<64, 9, 4, 128, 256, 2, 2>
      <<<dim3(2, 128), 256, 0, stream>>>(o1, w2r, eb2, eg2, ebb2, em2, ev2,
                                         pair_e, o2);
  // block3: 128->256, L128->64
  mfma_conv<128, 11, 5, 256, 128, 2, 2>
      <<<dim3(2, 128), 256, 0, stream>>>(o2, w3r, eb3, eg3, ebb3, em3, ev3,
                                         pair_e, o3);
  // block4: 256->512, L64->32
  mfma_conv<256, 25, 12, 512, 64, 4, 1>
      <<<dim3(2, 128), 256, 0, stream>>>(o3, w4r, eb4, eg4, ebb4, em4, ev4,
                                         pair_e, o4);

  combine_kernel<<<64, 256, 0, stream>>>(o4, pair_g, g);
  head_kernel<<<64, 256, 0, stream>>>(g, f1w, f1b, f2w, f2b, f3w, f3b, out);
}

// Round 4
// 474.587 us; speedup vs baseline: 5.0687x; 1.4700x over previous
//
#include <hip/hip_runtime.h>
#include <math.h>

#define BN_EPS 1e-5f

typedef _Float16 half8 __attribute__((ext_vector_type(8)));
typedef float floatx4 __attribute__((ext_vector_type(4)));

// async global->LDS, 16B per lane: LDS dst = uniform base + lane*16
__device__ __forceinline__ void gl_lds16(const _Float16* g, _Float16* l) {
  __builtin_amdgcn_global_load_lds(
      (const __attribute__((address_space(1))) unsigned int*)g,
      (__attribute__((address_space(3))) unsigned int*)l, 16, 0, 0);
}

// ---------------------------------------------------------------------------
// Kernel A: conv1 (k=3, pad=1, 1->16 ch) + ReLU, and channel means (pooled).
// ---------------------------------------------------------------------------
__global__ __launch_bounds__(256) void conv1_kernel(
    const float* __restrict__ x, const float* __restrict__ w,
    const float* __restrict__ bias, float* __restrict__ h,
    float* __restrict__ pooled) {
  __shared__ float xs[514];
  __shared__ float psum[256];
  const int b = blockIdx.x;
  const int t = threadIdx.x;
  for (int i = t; i < 512; i += 256) xs[i + 1] = x[b * 512 + i];
  if (t == 0) { xs[0] = 0.f; xs[513] = 0.f; }
  __syncthreads();
  const int c  = t >> 4;
  const int l0 = (t & 15) * 32;
  const float w0 = w[c * 3 + 0], w1 = w[c * 3 + 1], w2 = w[c * 3 + 2];
  const float bb = bias[c];
  float s = 0.f;
  float* hrow = h + ((size_t)b * 16 + c) * 512;
  for (int j = 0; j < 32; ++j) {
    const int l = l0 + j;
    float v = fmaf(w0, xs[l], fmaf(w1, xs[l + 1], fmaf(w2, xs[l + 2], bb)));
    v = fmaxf(v, 0.f);
    hrow[l] = v;
    s += v;
  }
  psum[t] = s;
  __syncthreads();
  if ((t & 15) == 0) {
    float tot = 0.f;
    for (int k = 0; k < 16; ++k) tot += psum[t + k];
    pooled[b * 16 + c] = tot * (1.f / 512.f);
  }
}

// ---------------------------------------------------------------------------
// Kernel B: router. softmax -> top2 -> renormalized gates + cv^2 scalar.
// ---------------------------------------------------------------------------
__global__ void router_kernel(const float* __restrict__ pooled,
                              const float* __restrict__ rw,
                              const float* __restrict__ rb,
                              float* __restrict__ pair_g,
                              int* __restrict__ pair_e,
                              float* __restrict__ out_cv) {
  __shared__ float probs_l[64][8];
  __shared__ float mp[8];
  const int t = threadIdx.x;
  {
    float pl[16];
    for (int c = 0; c < 16; ++c) pl[c] = pooled[t * 16 + c];
    float lg[8];
    float mx = -1e30f;
    for (int e = 0; e < 8; ++e) {
      float a = rb[e];
      for (int c = 0; c < 16; ++c) a = fmaf(pl[c], rw[e * 16 + c], a);
      lg[e] = a;
      mx = fmaxf(mx, a);
    }
    float sum = 0.f;
    for (int e = 0; e < 8; ++e) { lg[e] = expf(lg[e] - mx); sum += lg[e]; }
    const float inv = 1.f / sum;
    for (int e = 0; e < 8; ++e) { lg[e] *= inv; probs_l[t][e] = lg[e]; }
    int e1 = 0; float p1 = lg[0];
    for (int e = 1; e < 8; ++e) if (lg[e] > p1) { p1 = lg[e]; e1 = e; }
    int e2 = -1; float p2 = -1.f;
    for (int e = 0; e < 8; ++e) if (e != e1 && lg[e] > p2) { p2 = lg[e]; e2 = e; }
    const float gs = 1.f / (p1 + p2);
    pair_e[2 * t]     = e1; pair_g[2 * t]     = p1 * gs;
    pair_e[2 * t + 1] = e2; pair_g[2 * t + 1] = p2 * gs;
  }
  __syncthreads();
  if (t < 8) {
    float s = 0.f;
    for (int b = 0; b < 64; ++b) s += probs_l[b][t];
    mp[t] = s * (1.f / 64.f);
  }
  __syncthreads();
  if (t == 0) {
    float mean = 0.f;
    for (int e = 0; e < 8; ++e) mean += mp[e];
    mean *= (1.f / 8.f);
    float var = 0.f;
    for (int e = 0; e < 8; ++e) { const float d = mp[e] - mean; var = fmaf(d, d, var); }
    var *= (1.f / 7.f);
    const float cv = sqrtf(var) / (mean + 1e-10f);
    *out_cv = cv * cv;
  }
}

// ---------------------------------------------------------------------------
// Weight repack: ew[e][co][ci][k] fp32 -> wrp[e][cic][dk][co][ci32] fp16.
// Thread = (e, cic, co, c32): reads K contiguous floats (each read once),
// writes K halfs, wave-coalesced per dk.
// ---------------------------------------------------------------------------
template <int CI, int K, int CO>
__global__ __launch_bounds__(256) void repack_kernel(
    const float* __restrict__ ew, _Float16* __restrict__ wrp) {
  constexpr int NCc = CI / 32;
  const int tid = blockIdx.x * 256 + threadIdx.x;
  const int c32 = tid & 31;
  int r = tid >> 5;
  const int co = r % CO; r /= CO;
  const int cic = r % NCc;
  const int e = r / NCc;
  const float* src = ew + ((size_t)(e * CO + co) * CI + cic * 32 + c32) * K;
  float v[K];
#pragma unroll
  for (int dk = 0; dk < K; ++dk) v[dk] = src[dk];
#pragma unroll
  for (int dk = 0; dk < K; ++dk)
    wrp[(((size_t)(e * NCc + cic) * K + dk) * CO + co) * 32 + c32] =
        (_Float16)v[dk];
}

// ---------------------------------------------------------------------------
// Block1 (fp32 vector conv, 16->64ch, L512->256), fp16 [pair][xp][co] out.
// ---------------------------------------------------------------------------
__global__ __launch_bounds__(256) void conv_block1(
    const float* __restrict__ in, const float* __restrict__ ew,
    const float* __restrict__ eb, const float* __restrict__ eg,
    const float* __restrict__ ebb, const float* __restrict__ em,
    const float* __restrict__ ev, const int* __restrict__ pair_e,
    _Float16* __restrict__ out) {
  constexpr int CI = 16, LIN = 512, K = 3, PAD = 1, CO = 64;
  constexpr int W_X  = 66;
  constexpr int W_XP = 68;
  constexpr int WROW = 66;
  __shared__ __align__(16) float xs[CI * W_XP];
  __shared__ __align__(16) float wls[CI * K * WROW];

  const int p  = blockIdx.y;
  const int t  = threadIdx.x;
  const int e  = pair_e[p];
  const int jt = blockIdx.x;
  const float* inp = in + (size_t)(p >> 1) * CI * LIN;
  const int cg = t & 31;
  const int jg = t >> 5;

  float acc0[8], acc1[8];
#pragma unroll
  for (int u = 0; u < 8; ++u) { acc0[u] = 0.f; acc1[u] = 0.f; }
  const int gx0 = jt * 64 - PAD;

  for (int i = t; i < CI * W_XP; i += 256) {
    const int ci = i / W_XP, w = i % W_XP;
    const int gi = gx0 + w;
    float v = 0.f;
    if (w < W_X && gi >= 0 && gi < LIN) v = inp[(size_t)ci * LIN + gi];
    xs[i] = v;
  }
  for (int i = t; i < CI * K * 64; i += 256) {
    const int co = i / (CI * K);
    const int r  = i % (CI * K);
    const int ci = r / K, k = r % K;
    wls[(ci * K + k) * WROW + co] =
        ew[(((size_t)e * CO + co) * CI + ci) * K + k];
  }
  __syncthreads();
  for (int ci = 0; ci < CI; ++ci) {
    const float* xrow = xs + ci * W_XP + jg * 8;
    const float* wrow = wls + ci * K * WROW + 2 * cg;
    float xw[8];
    {
      const float4 a = *(const float4*)(xrow);
      const float4 b = *(const float4*)(xrow + 4);
      xw[0] = a.x; xw[1] = a.y; xw[2] = a.z; xw[3] = a.w;
      xw[4] = b.x; xw[5] = b.y; xw[6] = b.z; xw[7] = b.w;
    }
#pragma unroll
    for (int dk = 0; dk < K; ++dk) {
      const float2 wv = *(const float2*)(wrow + dk * WROW);
#pragma unroll
      for (int u = 0; u < 8; ++u) {
        const float xv = xw[(dk + u) & 7];
        acc0[u] = fmaf(wv.x, xv, acc0[u]);
        acc1[u] = fmaf(wv.y, xv, acc1[u]);
      }
      if (dk + 1 < K) xw[dk & 7] = xrow[dk + 8];
    }
  }

  const int j0 = jt * 32 + jg * 4;
#pragma unroll
  for (int n = 0; n < 2; ++n) {
    const float* acc = n ? acc1 : acc0;
    const int co = 2 * cg + n;
    const int pe = e * CO + co;
    const float s   = eg[pe] * rsqrtf(ev[pe] + BN_EPS);
    const float off = fmaf(eb[pe] - em[pe], s, ebb[pe]);
#pragma unroll
    for (int q = 0; q < 4; ++q) {
      const float y0 = fmaxf(fmaf(acc[2 * q], s, off), 0.f);
      const float y1 = fmaxf(fmaf(acc[2 * q + 1], s, off), 0.f);
      out[((size_t)p * 256 + j0 + q) * CO + co] = (_Float16)fmaxf(y0, y1);
    }
  }
}

// ---------------------------------------------------------------------------
// MFMA conv block: conv K -> BN -> ReLU -> maxpool2 over 128 pairs.
//   D[co][x] = sum_{cic,dk,ci32} W[e][cic][dk][co][ci32] * X[p][x+dk-PAD][ci]
// Activations [pair][x][CI] fp16; weights repacked [e][cic][dk][co][ci32].
// Block 256 thr = 4 waves; tile BM=128 co x XN x-positions; wave-tile 64 x TN.
// A-tile (8 KB contiguous) staged via global_load_lds dwordx4, double-
// buffered, 1 barrier per (cic,dk) phase. B window staged once per cic.
// LDS rows = 32 halfs (64 B): 16-row b128 tiles are perfect bank partitions
// -> zero conflicts.
// ---------------------------------------------------------------------------
template <int CI, int K, int PAD, int CO, int LIN, int XN, int TN>
__global__ __launch_bounds__(256) void mfma_conv(
    const _Float16* __restrict__ xin, const _Float16* __restrict__ wrp,
    const float* __restrict__ eb, const float* __restrict__ eg,
    const float* __restrict__ ebb, const float* __restrict__ em,
    const float* __restrict__ ev, const int* __restrict__ pair_e,
    _Float16* __restrict__ out) {
  constexpr int BM  = 128;
  constexpr int NC  = CI / 32;
  constexpr int XWR = XN + K - 1;
  constexpr int NT  = TN / 16;
  constexpr int WN  = XN / TN;
  constexpr int NPH = NC * K;

  __shared__ __align__(16) _Float16 Ash[2 * BM * 32];
  __shared__ __align__(16) _Float16 Bsh[XWR * 32];
  __shared__ float sc[BM];
  __shared__ float of[BM];

  const int p  = blockIdx.y;
  const int t  = threadIdx.x;
  const int e  = pair_e[p];
  constexpr int XTN = LIN / XN;
  const int xt = blockIdx.x % XTN;
  const int ct = blockIdx.x / XTN;
  const int co0 = ct * BM;
  const int x0  = xt * XN;

  const int lane = t & 63;
  const int wave = t >> 6;
  const int wm = wave / WN;
  const int wn = wave % WN;
  const int lm = lane & 15;
  const int q  = lane >> 4;

  for (int i = t; i < BM; i += 256) {
    const int pe = e * CO + co0 + i;
    const float s = eg[pe] * rsqrtf(ev[pe] + BN_EPS);
    sc[i] = s;
    of[i] = fmaf(eb[pe] - em[pe], s, ebb[pe]);
  }

  floatx4 acc[4][NT];
#pragma unroll
  for (int a = 0; a < 4; ++a)
#pragma unroll
    for (int b = 0; b < NT; ++b) acc[a][b] = (floatx4){0.f, 0.f, 0.f, 0.f};

  const _Float16* xb = xin + (size_t)p * LIN * CI;

  auto stage_B = [&](int cic) {
    for (int c = t; c < XWR * 4; c += 256) {
      const int row = c >> 2, qq = c & 3;
      const int gx = x0 - PAD + row;
      uint4 v = {0u, 0u, 0u, 0u};
      if (gx >= 0 && gx < LIN)
        v = *(const uint4*)(xb + (size_t)gx * CI + cic * 32 + qq * 8);
      *(uint4*)(Bsh + row * 32 + qq * 8) = v;
    }
  };
  // A-tile for phase ph: 128 co rows x 32 ci halfs = 8 KB contiguous.
  auto stage_A = [&](int ph, int buf) {
    const int cic = ph / K, dk = ph % K;
    const _Float16* src =
        wrp + (((size_t)(e * NC + cic) * K + dk) * CO + co0) * 32;
    _Float16* dst = Ash + buf * (BM * 32);
#pragma unroll
    for (int c = 0; c < 2; ++c) {
      const int chunk = wave * 2 + c;   // 8 chunks of 1024 B
      gl_lds16(src + chunk * 512 + lane * 8, dst + chunk * 512);
    }
  };

  stage_B(0);
  stage_A(0, 0);
  __syncthreads();

  for (int ph = 0; ph < NPH; ++ph) {
    const int dk = ph % K;
    if (ph + 1 < NPH) stage_A(ph + 1, (ph + 1) & 1);
    {
      const _Float16* Ab = Ash + (ph & 1) * (BM * 32);
      half8 af[4], bf[NT];
#pragma unroll
      for (int mt = 0; mt < 4; ++mt)
        af[mt] = *(const half8*)(Ab + (wm * 64 + mt * 16 + lm) * 32 + q * 8);
#pragma unroll
      for (int nt = 0; nt < NT; ++nt)
        bf[nt] = *(const half8*)(Bsh + (wn * TN + nt * 16 + lm + dk) * 32 + q * 8);
#pragma unroll
      for (int mt = 0; mt < 4; ++mt)
#pragma unroll
        for (int nt = 0; nt < NT; ++nt)
          acc[mt][nt] = __builtin_amdgcn_mfma_f32_16x16x32_f16(
              af[mt], bf[nt], acc[mt][nt], 0, 0, 0);
    }
    __syncthreads();
    if (dk == K - 1 && ph + 1 < NPH) {
      stage_B((ph + 1) / K);
      __syncthreads();
    }
  }

  // Epilogue: BN + ReLU + maxpool2 (x pairs = adjacent lanes in C layout).
#pragma unroll
  for (int mt = 0; mt < 4; ++mt) {
#pragma unroll
    for (int nt = 0; nt < NT; ++nt) {
      union { _Float16 h[4]; uint2 u; } pk;
#pragma unroll
      for (int r = 0; r < 4; ++r) {
        const int co_l = wm * 64 + mt * 16 + q * 4 + r;
        float y = fmaxf(fmaf(acc[mt][nt][r], sc[co_l], of[co_l]), 0.f);
        const float yp = __shfl_xor(y, 1, 64);
        pk.h[r] = (_Float16)fmaxf(y, yp);
      }
      if ((lane & 1) == 0) {
        const int xg = x0 + wn * TN + nt * 16 + lm;
        const int xp = xg >> 1;
        const int cob = co0 + wm * 64 + mt * 16 + q * 4;
        *(uint2*)(out + ((size_t)p * (LIN / 2) + xp) * CO + cob) = pk.u;
      }
    }
  }
}

// ---------------------------------------------------------------------------
// Combine: mean over 32 positions of o4 [p][xp][512] fp16, gated sum.
// ---------------------------------------------------------------------------
__global__ __launch_bounds__(256) void combine_kernel(
    const _Float16* __restrict__ out4, const float* __restrict__ pair_g,
    float* __restrict__ g) {
  const int b = blockIdx.x, t = threadIdx.x;
  const float g0 = pair_g[2 * b], g1 = pair_g[2 * b + 1];
  const _Float16* a0 = out4 + (size_t)(2 * b) * 32 * 512;
  const _Float16* a1 = out4 + (size_t)(2 * b + 1) * 32 * 512;
  for (int c = t; c < 512; c += 256) {
    float s0 = 0.f, s1 = 0.f;
    for (int jj = 0; jj < 32; ++jj) {
      s0 += (float)a0[jj * 512 + c];
      s1 += (float)a1[jj * 512 + c];
    }
    g[b * 512 + c] = (g0 * s0 + g1 * s1) * (1.f / 32.f);
  }
}

// ---------------------------------------------------------------------------
// FC head (512->256 relu ->64 relu ->5). One block per sample.
// ---------------------------------------------------------------------------
__global__ __launch_bounds__(256) void head_kernel(
    const float* __restrict__ g, const float* __restrict__ w1,
    const float* __restrict__ b1, const float* __restrict__ w2,
    const float* __restrict__ b2, const float* __restrict__ w3,
    const float* __restrict__ b3, float* __restrict__ out) {
  __shared__ float gl[512];
  __shared__ float h1[256];
  __shared__ float h2[64];
  const int b = blockIdx.x, t = threadIdx.x;
  for (int i = t; i < 512; i += 256) gl[i] = g[b * 512 + i];
  __syncthreads();
  {
    float a = b1[t];
    const float* wr = w1 + (size_t)t * 512;
    for (int k = 0; k < 512; ++k) a = fmaf(gl[k], wr[k], a);
    h1[t] = fmaxf(a, 0.f);
  }
  __syncthreads();
  if (t < 64) {
    float a = b2[t];
    const float* wr = w2 + (size_t)t * 256;
    for (int k = 0; k < 256; ++k) a = fmaf(h1[k], wr[k], a);
    h2[t] = fmaxf(a, 0.f);
  }
  __syncthreads();
  if (t < 5) {
    float a = b3[t];
    const float* wr = w3 + (size_t)t * 64;
    for (int k = 0; k < 64; ++k) a = fmaf(h2[k], wr[k], a);
    out[b * 5 + t] = a;
  }
}

// ---------------------------------------------------------------------------
extern "C" void kernel_launch(void* const* d_in, const int* in_sizes, int n_in,
                              void* d_out, int out_size, void* d_ws,
                              size_t ws_size, hipStream_t stream) {
  const float* x   = (const float*)d_in[0];
  const float* c1w = (const float*)d_in[1];
  const float* c1b = (const float*)d_in[2];
  const float* ew1 = (const float*)d_in[3];
  const float* eb1 = (const float*)d_in[4];
  const float* eg1 = (const float*)d_in[5];
  const float* ebb1= (const float*)d_in[6];
  const float* em1 = (const float*)d_in[7];
  const float* ev1 = (const float*)d_in[8];
  const float* ew2 = (const float*)d_in[9];
  const float* eb2 = (const float*)d_in[10];
  const float* eg2 = (const float*)d_in[11];
  const float* ebb2= (const float*)d_in[12];
  const float* em2 = (const float*)d_in[13];
  const float* ev2 = (const float*)d_in[14];
  const float* ew3 = (const float*)d_in[15];
  const float* eb3 = (const float*)d_in[16];
  const float* eg3 = (const float*)d_in[17];
  const float* ebb3= (const float*)d_in[18];
  const float* em3 = (const float*)d_in[19];
  const float* ev3 = (const float*)d_in[20];
  const float* ew4 = (const float*)d_in[21];
  const float* eb4 = (const float*)d_in[22];
  const float* eg4 = (const float*)d_in[23];
  const float* ebb4= (const float*)d_in[24];
  const float* em4 = (const float*)d_in[25];
  const float* ev4 = (const float*)d_in[26];
  const float* rw  = (const float*)d_in[27];
  const float* rb  = (const float*)d_in[28];
  const float* f1w = (const float*)d_in[29];
  const float* f1b = (const float*)d_in[30];
  const float* f2w = (const float*)d_in[31];
  const float* f2b = (const float*)d_in[32];
  const float* f3w = (const float*)d_in[33];
  const float* f3b = (const float*)d_in[34];
  float* out = (float*)d_out;

  // workspace layout
  float* ws      = (float*)d_ws;
  float* h       = ws;                       // 524288 f32
  float* pooled  = h + 524288;               // 1024
  float* pair_g  = pooled + 1024;            // 128
  int*   pair_e  = (int*)(pair_g + 128);     // 128
  _Float16* o1   = (_Float16*)(ws + 525568);   // 128*256*64
  _Float16* o2   = o1 + 2097152;               // 128*128*128
  _Float16* o3   = o2 + 2097152;               // 128*64*256
  _Float16* o4   = o3 + 2097152;               // 128*32*512
  _Float16* w2r  = o4 + 2097152;               // 8*2*9*128*32   = 589,824
  _Float16* w3r  = w2r + 589824;               // 8*4*11*256*32  = 2,883,584
  _Float16* w4r  = w3r + 2883584;              // 8*8*25*512*32  = 26,214,400
  float* g       = (float*)(w4r + 26214400);   // 64*512 f32

  conv1_kernel<<<64, 256, 0, stream>>>(x, c1w, c1b, h, pooled);
  router_kernel<<<1, 64, 0, stream>>>(pooled, rw, rb, pair_g, pair_e, out + 320);

  // weight repacks: [e][co][ci][k] fp32 -> [e][cic][dk][co][ci32] fp16
  repack_kernel<64, 9, 128><<<8 * 2 * 128 * 32 / 256, 256, 0, stream>>>(ew2, w2r);
  repack_kernel<128, 11, 256><<<8 * 4 * 256 * 32 / 256, 256, 0, stream>>>(ew3, w3r);
  repack_kernel<256, 25, 512><<<8 * 8 * 512 * 32 / 256, 256, 0, stream>>>(ew4, w4r);

  // block1: fp32 vector conv, 16->64, L512->256, fp16 transposed out
  conv_block1<<<dim3(8, 128), 256, 0, stream>>>(h, ew1, eb1, eg1, ebb1, em1,
                                                ev1, pair_e, o1);
  // block2: 64->128, L256->128   grid (1 co-tile * 2 x-tiles, 128)
  mfma_conv<64, 9, 4, 128, 256, 128, 64>
      <<<dim3(2, 128), 256, 0, stream>>>(o1, w2r, eb2, eg2, ebb2, em2, ev2,
                                         pair_e, o2);
  // block3: 128->256, L128->64  grid (2 co-tiles * 1 x-tile, 128)
  mfma_conv<128, 11, 5, 256, 128, 128, 64>
      <<<dim3(2, 128), 256, 0, stream>>>(o2, w3r, eb3, eg3, ebb3, em3, ev3,
                                         pair_e, o3);
  // block4: 256->512, L64->32   grid (4 co-tiles * 1 x-tile, 128)
  mfma_conv<256, 25, 12, 512, 64, 64, 32>
      <<<dim3(4, 128), 256, 0, stream>>>(o3, w4r, eb4, eg4, ebb4, em4, ev4,
                                         pair_e, o4);

  combine_kernel<<<64, 256, 0, stream>>>(o4, pair_g, g);
  head_kernel<<<64, 256, 0, stream>>>(g, f1w, f1b, f2w, f2b, f3w, f3b, out);
}

// Round 5
// 387.575 us; speedup vs baseline: 6.2067x; 1.2245x over previous
//
#include <hip/hip_runtime.h>
#include <math.h>

#define BN_EPS 1e-5f

typedef _Float16 half8 __attribute__((ext_vector_type(8)));
typedef float floatx16 __attribute__((ext_vector_type(16)));

// ---------------------------------------------------------------------------
// Kernel A: conv1 (k=3, pad=1, 1->16 ch) + ReLU, and channel means (pooled).
// ---------------------------------------------------------------------------
__global__ __launch_bounds__(256) void conv1_kernel(
    const float* __restrict__ x, const float* __restrict__ w,
    const float* __restrict__ bias, float* __restrict__ h,
    float* __restrict__ pooled) {
  __shared__ float xs[514];
  __shared__ float psum[256];
  const int b = blockIdx.x;
  const int t = threadIdx.x;
  for (int i = t; i < 512; i += 256) xs[i + 1] = x[b * 512 + i];
  if (t == 0) { xs[0] = 0.f; xs[513] = 0.f; }
  __syncthreads();
  const int c  = t >> 4;
  const int l0 = (t & 15) * 32;
  const float w0 = w[c * 3 + 0], w1 = w[c * 3 + 1], w2 = w[c * 3 + 2];
  const float bb = bias[c];
  float s = 0.f;
  float* hrow = h + ((size_t)b * 16 + c) * 512;
  for (int j = 0; j < 32; ++j) {
    const int l = l0 + j;
    float v = fmaf(w0, xs[l], fmaf(w1, xs[l + 1], fmaf(w2, xs[l + 2], bb)));
    v = fmaxf(v, 0.f);
    hrow[l] = v;
    s += v;
  }
  psum[t] = s;
  __syncthreads();
  if ((t & 15) == 0) {
    float tot = 0.f;
    for (int k = 0; k < 16; ++k) tot += psum[t + k];
    pooled[b * 16 + c] = tot * (1.f / 512.f);
  }
}

// ---------------------------------------------------------------------------
// Kernel B: router. softmax -> top2 -> renormalized gates + cv^2 scalar.
// ---------------------------------------------------------------------------
__global__ void router_kernel(const float* __restrict__ pooled,
                              const float* __restrict__ rw,
                              const float* __restrict__ rb,
                              float* __restrict__ pair_g,
                              int* __restrict__ pair_e,
                              float* __restrict__ out_cv) {
  __shared__ float probs_l[64][8];
  __shared__ float mp[8];
  const int t = threadIdx.x;
  {
    float pl[16];
    for (int c = 0; c < 16; ++c) pl[c] = pooled[t * 16 + c];
    float lg[8];
    float mx = -1e30f;
    for (int e = 0; e < 8; ++e) {
      float a = rb[e];
      for (int c = 0; c < 16; ++c) a = fmaf(pl[c], rw[e * 16 + c], a);
      lg[e] = a;
      mx = fmaxf(mx, a);
    }
    float sum = 0.f;
    for (int e = 0; e < 8; ++e) { lg[e] = expf(lg[e] - mx); sum += lg[e]; }
    const float inv = 1.f / sum;
    for (int e = 0; e < 8; ++e) { lg[e] *= inv; probs_l[t][e] = lg[e]; }
    int e1 = 0; float p1 = lg[0];
    for (int e = 1; e < 8; ++e) if (lg[e] > p1) { p1 = lg[e]; e1 = e; }
    int e2 = -1; float p2 = -1.f;
    for (int e = 0; e < 8; ++e) if (e != e1 && lg[e] > p2) { p2 = lg[e]; e2 = e; }
    const float gs = 1.f / (p1 + p2);
    pair_e[2 * t]     = e1; pair_g[2 * t]     = p1 * gs;
    pair_e[2 * t + 1] = e2; pair_g[2 * t + 1] = p2 * gs;
  }
  __syncthreads();
  if (t < 8) {
    float s = 0.f;
    for (int b = 0; b < 64; ++b) s += probs_l[b][t];
    mp[t] = s * (1.f / 64.f);
  }
  __syncthreads();
  if (t == 0) {
    float mean = 0.f;
    for (int e = 0; e < 8; ++e) mean += mp[e];
    mean *= (1.f / 8.f);
    float var = 0.f;
    for (int e = 0; e < 8; ++e) { const float d = mp[e] - mean; var = fmaf(d, d, var); }
    var *= (1.f / 7.f);
    const float cv = sqrtf(var) / (mean + 1e-10f);
    *out_cv = cv * cv;
  }
}

// ---------------------------------------------------------------------------
// Weight repack: ew[e][co][ci][k] fp32 -> wrp[e][cic][dkp][co][ci32] fp16,
// with dk padded to KP (zero taps for dk >= K, so RING | KP in the consumer).
// Thread = (e, cic, co, c32): reads K contiguous floats once, writes KP halfs.
// ---------------------------------------------------------------------------
template <int CI, int K, int KP, int CO>
__global__ __launch_bounds__(256) void repack_kernel(
    const float* __restrict__ ew, _Float16* __restrict__ wrp) {
  constexpr int NCc = CI / 32;
  const int tid = blockIdx.x * 256 + threadIdx.x;
  const int c32 = tid & 31;
  int r = tid >> 5;
  const int co = r % CO; r /= CO;
  const int cic = r % NCc;
  const int e = r / NCc;
  const float* src = ew + ((size_t)(e * CO + co) * CI + cic * 32 + c32) * K;
  float v[K];
#pragma unroll
  for (int dk = 0; dk < K; ++dk) v[dk] = src[dk];
#pragma unroll
  for (int dk = 0; dk < KP; ++dk)
    wrp[(((size_t)(e * NCc + cic) * KP + dk) * CO + co) * 32 + c32] =
        (_Float16)(dk < K ? v[dk] : 0.f);
}

// ---------------------------------------------------------------------------
// Block1 (fp32 vector conv, 16->64ch, L512->256), fp16 [pair][xp][co] out.
// ---------------------------------------------------------------------------
__global__ __launch_bounds__(256) void conv_block1(
    const float* __restrict__ in, const float* __restrict__ ew,
    const float* __restrict__ eb, const float* __restrict__ eg,
    const float* __restrict__ ebb, const float* __restrict__ em,
    const float* __restrict__ ev, const int* __restrict__ pair_e,
    _Float16* __restrict__ out) {
  constexpr int CI = 16, LIN = 512, K = 3, PAD = 1, CO = 64;
  constexpr int W_X  = 66;
  constexpr int W_XP = 68;
  constexpr int WROW = 66;
  __shared__ __align__(16) float xs[CI * W_XP];
  __shared__ __align__(16) float wls[CI * K * WROW];

  const int p  = blockIdx.y;
  const int t  = threadIdx.x;
  const int e  = pair_e[p];
  const int jt = blockIdx.x;
  const float* inp = in + (size_t)(p >> 1) * CI * LIN;
  const int cg = t & 31;
  const int jg = t >> 5;

  float acc0[8], acc1[8];
#pragma unroll
  for (int u = 0; u < 8; ++u) { acc0[u] = 0.f; acc1[u] = 0.f; }
  const int gx0 = jt * 64 - PAD;

  for (int i = t; i < CI * W_XP; i += 256) {
    const int ci = i / W_XP, w = i % W_XP;
    const int gi = gx0 + w;
    float v = 0.f;
    if (w < W_X && gi >= 0 && gi < LIN) v = inp[(size_t)ci * LIN + gi];
    xs[i] = v;
  }
  for (int i = t; i < CI * K * 64; i += 256) {
    const int co = i / (CI * K);
    const int r  = i % (CI * K);
    const int ci = r / K, k = r % K;
    wls[(ci * K + k) * WROW + co] =
        ew[(((size_t)e * CO + co) * CI + ci) * K + k];
  }
  __syncthreads();
  for (int ci = 0; ci < CI; ++ci) {
    const float* xrow = xs + ci * W_XP + jg * 8;
    const float* wrow = wls + ci * K * WROW + 2 * cg;
    float xw[8];
    {
      const float4 a = *(const float4*)(xrow);
      const float4 b = *(const float4*)(xrow + 4);
      xw[0] = a.x; xw[1] = a.y; xw[2] = a.z; xw[3] = a.w;
      xw[4] = b.x; xw[5] = b.y; xw[6] = b.z; xw[7] = b.w;
    }
#pragma unroll
    for (int dk = 0; dk < K; ++dk) {
      const float2 wv = *(const float2*)(wrow + dk * WROW);
#pragma unroll
      for (int u = 0; u < 8; ++u) {
        const float xv = xw[(dk + u) & 7];
        acc0[u] = fmaf(wv.x, xv, acc0[u]);
        acc1[u] = fmaf(wv.y, xv, acc1[u]);
      }
      if (dk + 1 < K) xw[dk & 7] = xrow[dk + 8];
    }
  }

  const int j0 = jt * 32 + jg * 4;
#pragma unroll
  for (int n = 0; n < 2; ++n) {
    const float* acc = n ? acc1 : acc0;
    const int co = 2 * cg + n;
    const int pe = e * CO + co;
    const float s   = eg[pe] * rsqrtf(ev[pe] + BN_EPS);
    const float off = fmaf(eb[pe] - em[pe], s, ebb[pe]);
#pragma unroll
    for (int q = 0; q < 4; ++q) {
      const float y0 = fmaxf(fmaf(acc[2 * q], s, off), 0.f);
      const float y1 = fmaxf(fmaf(acc[2 * q + 1], s, off), 0.f);
      out[((size_t)p * 256 + j0 + q) * CO + co] = (_Float16)fmaxf(y0, y1);
    }
  }
}

// ---------------------------------------------------------------------------
// MFMA conv block v2: conv -> BN -> ReLU -> maxpool2 over 128 pairs.
// 32x32x16_f16 MFMA. Block = 256 thr = 4 waves partitioning BM co rows
// (A read ONCE per block). A streams global->VGPR in a register ring
// (lookahead RING-1 phases, RING | KP so ring indices are static and the
// cic boundary sits outside the unrolled body). LDS holds only the B
// x-window [XWR][32] per ci-chunk, double-buffered; ONE barrier per cic.
// Weights pre-repacked to the linear phase stream [e][cic][dkp][co][ci32].
// ---------------------------------------------------------------------------
template <int CI, int K, int KP, int PAD, int CO, int BM, int LIN, int XN,
          int RING>
__global__ __launch_bounds__(256, 1) void mfma_conv(
    const _Float16* __restrict__ xin, const _Float16* __restrict__ wrp,
    const float* __restrict__ eb, const float* __restrict__ eg,
    const float* __restrict__ ebb, const float* __restrict__ em,
    const float* __restrict__ ev, const int* __restrict__ pair_e,
    _Float16* __restrict__ out) {
  constexpr int NC  = CI / 32;
  constexpr int NPH = NC * KP;
  constexpr int MT  = BM / 128;   // 32-co tiles per wave
  constexpr int NT  = XN / 32;    // 32-x tiles per wave
  constexpr int XWR = XN + KP - 1;
  constexpr int XTN = LIN / XN;
  constexpr int WSL = BM / 4;     // co rows per wave

  __shared__ __align__(16) _Float16 Bsh[2][XWR * 32];
  __shared__ float sc[BM];
  __shared__ float of[BM];

  const int p  = blockIdx.y;
  const int t  = threadIdx.x;
  const int e  = pair_e[p];
  const int xt = blockIdx.x % XTN;
  const int ct = blockIdx.x / XTN;
  const int cob = ct * BM;
  const int x0  = xt * XN;

  const int lane = t & 63;
  const int wave = t >> 6;
  const int l31 = lane & 31;
  const int lhi = lane >> 5;

  for (int i = t; i < BM; i += 256) {
    const int pe = e * CO + cob + i;
    const float s = eg[pe] * rsqrtf(ev[pe] + BN_EPS);
    sc[i] = s;
    of[i] = fmaf(eb[pe] - em[pe], s, ebb[pe]);
  }

  floatx16 acc[MT][NT];
#pragma unroll
  for (int a = 0; a < MT; ++a)
#pragma unroll
    for (int b = 0; b < NT; ++b)
#pragma unroll
      for (int r = 0; r < 16; ++r) acc[a][b][r] = 0.f;

  const _Float16* xb = xin + (size_t)p * LIN * CI;
  auto stage_B = [&](int cic, int buf) {
    for (int c = t; c < XWR * 4; c += 256) {
      const int row = c >> 2, qq = c & 3;
      const int gx = x0 - PAD + row;
      uint4 v = {0u, 0u, 0u, 0u};
      if (gx >= 0 && gx < LIN)
        v = *(const uint4*)(xb + (size_t)gx * CI + cic * 32 + qq * 8);
      *(uint4*)(&Bsh[buf][row * 32 + qq * 8]) = v;
    }
  };

  // A stream: phase ph lives at wrp + ((e*NPH + ph)*CO + co)*32
  const _Float16* Abase = wrp + ((size_t)e * NPH * CO + cob) * 32 +
                          (size_t)(wave * WSL + l31) * 32 + lhi * 8;
  half8 Ar[RING][MT][2];
  auto load_A = [&](int ph, half8 (&dst)[MT][2]) {
    if (ph >= NPH) ph = NPH - 1;
    const _Float16* src = Abase + (size_t)ph * (CO * 32);
#pragma unroll
    for (int mt = 0; mt < MT; ++mt)
#pragma unroll
      for (int ks = 0; ks < 2; ++ks)
        dst[mt][ks] = *(const half8*)(src + mt * 32 * 32 + ks * 16);
  };

  stage_B(0, 0);
#pragma unroll
  for (int d = 0; d < RING; ++d) load_A(d, Ar[d]);
  __syncthreads();
  if (NC > 1) stage_B(1, 1);

  int dk = 0, cic = 0;
  for (int ph0 = 0; ph0 < NPH; ph0 += RING) {
    if (dk == KP) {  // cic boundary: RING | KP puts it here, outside unroll
      dk = 0; ++cic;
      __syncthreads();
      if (cic + 1 < NC) stage_B(cic + 1, (cic + 1) & 1);
    }
    const _Float16* Bb = &Bsh[cic & 1][0];
#pragma unroll
    for (int d = 0; d < RING; ++d) {
      half8 bf[NT][2];
#pragma unroll
      for (int nt = 0; nt < NT; ++nt)
#pragma unroll
        for (int ks = 0; ks < 2; ++ks)
          bf[nt][ks] = *(const half8*)(Bb + (nt * 32 + l31 + dk) * 32 +
                                       ks * 16 + lhi * 8);
#pragma unroll
      for (int mt = 0; mt < MT; ++mt)
#pragma unroll
        for (int nt = 0; nt < NT; ++nt)
#pragma unroll
          for (int ks = 0; ks < 2; ++ks)
            acc[mt][nt] = __builtin_amdgcn_mfma_f32_32x32x16_f16(
                Ar[d][mt][ks], bf[nt][ks], acc[mt][nt], 0, 0, 0);
      load_A(ph0 + d + RING, Ar[d]);
      ++dk;
    }
  }

  // Epilogue: BN + ReLU + maxpool2.
  // 32x32 C layout: x = lane&31 (adjacent-lane pairs pool), co row =
  // (reg&3) + 8*(reg>>2) + 4*(lane>>5).
#pragma unroll
  for (int mt = 0; mt < MT; ++mt) {
#pragma unroll
    for (int nt = 0; nt < NT; ++nt) {
#pragma unroll
      for (int rq = 0; rq < 4; ++rq) {
        union { _Float16 h[4]; uint2 u; } pk;
#pragma unroll
        for (int j = 0; j < 4; ++j) {
          const int co_l = wave * WSL + mt * 32 + 8 * rq + 4 * lhi + j;
          float y = fmaxf(fmaf(acc[mt][nt][rq * 4 + j], sc[co_l], of[co_l]),
                          0.f);
          const float yp = __shfl_xor(y, 1, 64);
          pk.h[j] = (_Float16)fmaxf(y, yp);
        }
        if ((lane & 1) == 0) {
          const int xp = (x0 + nt * 32 + l31) >> 1;
          const int co = cob + wave * WSL + mt * 32 + 8 * rq + 4 * lhi;
          *(uint2*)(out + ((size_t)p * (LIN / 2) + xp) * CO + co) = pk.u;
        }
      }
    }
  }
}

// ---------------------------------------------------------------------------
// Combine: mean over 32 positions of o4 [p][xp][512] fp16, gated sum.
// ---------------------------------------------------------------------------
__global__ __launch_bounds__(256) void combine_kernel(
    const _Float16* __restrict__ out4, const float* __restrict__ pair_g,
    float* __restrict__ g) {
  const int b = blockIdx.x, t = threadIdx.x;
  const float g0 = pair_g[2 * b], g1 = pair_g[2 * b + 1];
  const _Float16* a0 = out4 + (size_t)(2 * b) * 32 * 512;
  const _Float16* a1 = out4 + (size_t)(2 * b + 1) * 32 * 512;
  for (int c = t; c < 512; c += 256) {
    float s0 = 0.f, s1 = 0.f;
    for (int jj = 0; jj < 32; ++jj) {
      s0 += (float)a0[jj * 512 + c];
      s1 += (float)a1[jj * 512 + c];
    }
    g[b * 512 + c] = (g0 * s0 + g1 * s1) * (1.f / 32.f);
  }
}

// ---------------------------------------------------------------------------
// FC head (512->256 relu ->64 relu ->5). One block per sample.
// ---------------------------------------------------------------------------
__global__ __launch_bounds__(256) void head_kernel(
    const float* __restrict__ g, const float* __restrict__ w1,
    const float* __restrict__ b1, const float* __restrict__ w2,
    const float* __restrict__ b2, const float* __restrict__ w3,
    const float* __restrict__ b3, float* __restrict__ out) {
  __shared__ float gl[512];
  __shared__ float h1[256];
  __shared__ float h2[64];
  const int b = blockIdx.x, t = threadIdx.x;
  for (int i = t; i < 512; i += 256) gl[i] = g[b * 512 + i];
  __syncthreads();
  {
    float a = b1[t];
    const float* wr = w1 + (size_t)t * 512;
    for (int k = 0; k < 512; ++k) a = fmaf(gl[k], wr[k], a);
    h1[t] = fmaxf(a, 0.f);
  }
  __syncthreads();
  if (t < 64) {
    float a = b2[t];
    const float* wr = w2 + (size_t)t * 256;
    for (int k = 0; k < 256; ++k) a = fmaf(h1[k], wr[k], a);
    h2[t] = fmaxf(a, 0.f);
  }
  __syncthreads();
  if (t < 5) {
    float a = b3[t];
    const float* wr = w3 + (size_t)t * 64;
    for (int k = 0; k < 64; ++k) a = fmaf(h2[k], wr[k], a);
    out[b * 5 + t] = a;
  }
}

// ---------------------------------------------------------------------------
extern "C" void kernel_launch(void* const* d_in, const int* in_sizes, int n_in,
                              void* d_out, int out_size, void* d_ws,
                              size_t ws_size, hipStream_t stream) {
  const float* x   = (const float*)d_in[0];
  const float* c1w = (const float*)d_in[1];
  const float* c1b = (const float*)d_in[2];
  const float* ew1 = (const float*)d_in[3];
  const float* eb1 = (const float*)d_in[4];
  const float* eg1 = (const float*)d_in[5];
  const float* ebb1= (const float*)d_in[6];
  const float* em1 = (const float*)d_in[7];
  const float* ev1 = (const float*)d_in[8];
  const float* ew2 = (const float*)d_in[9];
  const float* eb2 = (const float*)d_in[10];
  const float* eg2 = (const float*)d_in[11];
  const float* ebb2= (const float*)d_in[12];
  const float* em2 = (const float*)d_in[13];
  const float* ev2 = (const float*)d_in[14];
  const float* ew3 = (const float*)d_in[15];
  const float* eb3 = (const float*)d_in[16];
  const float* eg3 = (const float*)d_in[17];
  const float* ebb3= (const float*)d_in[18];
  const float* em3 = (const float*)d_in[19];
  const float* ev3 = (const float*)d_in[20];
  const float* ew4 = (const float*)d_in[21];
  const float* eb4 = (const float*)d_in[22];
  const float* eg4 = (const float*)d_in[23];
  const float* ebb4= (const float*)d_in[24];
  const float* em4 = (const float*)d_in[25];
  const float* ev4 = (const float*)d_in[26];
  const float* rw  = (const float*)d_in[27];
  const float* rb  = (const float*)d_in[28];
  const float* f1w = (const float*)d_in[29];
  const float* f1b = (const float*)d_in[30];
  const float* f2w = (const float*)d_in[31];
  const float* f2b = (const float*)d_in[32];
  const float* f3w = (const float*)d_in[33];
  const float* f3b = (const float*)d_in[34];
  float* out = (float*)d_out;

  // workspace layout
  float* ws      = (float*)d_ws;
  float* h       = ws;                       // 524288 f32
  float* pooled  = h + 524288;               // 1024
  float* pair_g  = pooled + 1024;            // 128
  int*   pair_e  = (int*)(pair_g + 128);     // 128
  _Float16* o1   = (_Float16*)(ws + 525568);   // 128*256*64
  _Float16* o2   = o1 + 2097152;               // 128*128*128
  _Float16* o3   = o2 + 2097152;               // 128*64*256
  _Float16* o4   = o3 + 2097152;               // 128*32*512
  _Float16* w2r  = o4 + 2097152;               // 8*2*10*128*32  = 655,360
  _Float16* w3r  = w2r + 655360;               // 8*4*12*256*32  = 3,145,728
  _Float16* w4r  = w3r + 3145728;              // 8*8*25*512*32  = 26,214,400
  float* g       = (float*)(w4r + 26214400);   // 64*512 f32

  conv1_kernel<<<64, 256, 0, stream>>>(x, c1w, c1b, h, pooled);
  router_kernel<<<1, 64, 0, stream>>>(pooled, rw, rb, pair_g, pair_e, out + 320);

  // weight repacks: [e][co][ci][k] fp32 -> [e][cic][dkp][co][ci32] fp16
  repack_kernel<64, 9, 10, 128><<<8 * 2 * 128 * 32 / 256, 256, 0, stream>>>(ew2, w2r);
  repack_kernel<128, 11, 12, 256><<<8 * 4 * 256 * 32 / 256, 256, 0, stream>>>(ew3, w3r);
  repack_kernel<256, 25, 25, 512><<<8 * 8 * 512 * 32 / 256, 256, 0, stream>>>(ew4, w4r);

  // block1: fp32 vector conv, 16->64, L512->256, fp16 transposed out
  conv_block1<<<dim3(8, 128), 256, 0, stream>>>(h, ew1, eb1, eg1, ebb1, em1,
                                                ev1, pair_e, o1);
  // block2: 64->128, L256->128.  BM=128 (MT=1), XN=128 (NT=4), KP=10, RING=5.
  mfma_conv<64, 9, 10, 4, 128, 128, 256, 128, 5>
      <<<dim3(2, 128), 256, 0, stream>>>(o1, w2r, eb2, eg2, ebb2, em2, ev2,
                                         pair_e, o2);
  // block3: 128->256, L128->64. BM=256 (MT=2), XN=64 (NT=2), KP=12, RING=4.
  mfma_conv<128, 11, 12, 5, 256, 256, 128, 64, 4>
      <<<dim3(2, 128), 256, 0, stream>>>(o2, w3r, eb3, eg3, ebb3, em3, ev3,
                                         pair_e, o3);
  // block4: 256->512, L64->32.  BM=256 (MT=2), XN=64 (NT=2), KP=25, RING=5.
  mfma_conv<256, 25, 25, 12, 512, 256, 64, 64, 5>
      <<<dim3(2, 128), 256, 0, stream>>>(o3, w4r, eb4, eg4, ebb4, em4, ev4,
                                         pair_e, o4);

  combine_kernel<<<64, 256, 0, stream>>>(o4, pair_g, g);
  head_kernel<<<64, 256, 0, stream>>>(g, f1w, f1b, f2w, f2b, f3w, f3b, out);
}